// Round 2
// baseline (2846.884 us; speedup 1.0000x reference)
//
#include <hip/hip_runtime.h>
#include <math.h>

// Problem constants
#define B_   16
#define C_   256
#define N_   16384      // H*W
#define NH_  4
#define G_   8
#define CPG_ 32

// Workspace layout (float offsets)
#define OFF_SUM  0        // [B][C]
#define OFF_SQ   4096     // [B][C]
#define OFF_S    8192     // [B][C] folded GN scale
#define OFF_T    12288    // [B][C] folded GN shift
#define OFF_M    16384    // [B][4][16][16]
#define OFF_Z    32768    // [B][64]
#define OFF_GATE 33792    // [B]
#define OFF_WT   33808    // [256][192] transposed Wk|Wv|Wq columns

// ---------------------------------------------------------------------------
// K1: per-(b,c) sum and sumsq. One block per (b,c).
// ---------------------------------------------------------------------------
__global__ __launch_bounds__(256) void k_stats(const float* __restrict__ x,
                                               float* __restrict__ ws) {
    const int bc = blockIdx.x;
    const float4* p4 = (const float4*)(x + (size_t)bc * N_);
    float s = 0.f, q = 0.f;
    #pragma unroll 4
    for (int i = threadIdx.x; i < N_ / 4; i += 256) {
        float4 v = p4[i];
        s += v.x + v.y + v.z + v.w;
        q += v.x * v.x + v.y * v.y + v.z * v.z + v.w * v.w;
    }
    #pragma unroll
    for (int o = 32; o > 0; o >>= 1) {
        s += __shfl_down(s, o);
        q += __shfl_down(q, o);
    }
    __shared__ float ls[4], lq[4];
    const int wid = threadIdx.x >> 6, lane = threadIdx.x & 63;
    if (lane == 0) { ls[wid] = s; lq[wid] = q; }
    __syncthreads();
    if (threadIdx.x == 0) {
        ws[OFF_SUM + bc] = ls[0] + ls[1] + ls[2] + ls[3];
        ws[OFF_SQ  + bc] = lq[0] + lq[1] + lq[2] + lq[3];
    }
}

// ---------------------------------------------------------------------------
// K_tr: transpose Wk/Wv/Wq into [c][192] column layout.
// ---------------------------------------------------------------------------
__global__ void k_tr(const float* __restrict__ Wk, const float* __restrict__ Wv,
                     const float* __restrict__ Wq, float* __restrict__ ws) {
    const int c = blockIdx.x;
    const int t = threadIdx.x;     // 0..191
    float v;
    if (t < 64)       v = Wk[t * C_ + c];
    else if (t < 128) v = Wv[(t - 64) * C_ + c];
    else              v = Wq[(t - 128) * C_ + c];
    ws[OFF_WT + c * 192 + t] = v;
}

// ---------------------------------------------------------------------------
// K2: per-batch prep — GN fold, gate MLP, M/Z warm-start init.
// ---------------------------------------------------------------------------
__global__ __launch_bounds__(256) void k_prep(
        const float* __restrict__ gnw, const float* __restrict__ gnb,
        const float* __restrict__ M0,  const float* __restrict__ Z0,
        const float* __restrict__ g1w, const float* __restrict__ g1b,
        const float* __restrict__ g2w, const float* __restrict__ g2b,
        float* __restrict__ ws, float* __restrict__ out_gate) {
    const int b = blockIdx.x, t = threadIdx.x;
    __shared__ float mu[G_], rs[G_];
    __shared__ float pooled[C_];
    __shared__ float hidden[64];

    if (t < G_) {
        float S = 0.f, Q = 0.f;
        for (int c = t * CPG_; c < (t + 1) * CPG_; ++c) {
            S += ws[OFF_SUM + b * C_ + c];
            Q += ws[OFF_SQ  + b * C_ + c];
        }
        const float cnt = (float)(CPG_ * N_);
        const float m = S / cnt;
        const float var = Q / cnt - m * m;
        mu[t] = m;
        rs[t] = rsqrtf(var + 1e-5f);
    }
    __syncthreads();
    {
        const int c = t;
        const int g = c / CPG_;
        const float sc = rs[g] * gnw[c];
        const float tc = gnb[c] - mu[g] * sc;
        ws[OFF_S + b * C_ + c] = sc;
        ws[OFF_T + b * C_ + c] = tc;
        const float meanc = ws[OFF_SUM + b * C_ + c] * (1.f / (float)N_);
        pooled[c] = meanc * sc + tc;
    }
    __syncthreads();
    if (t < 64) {
        float a = g1b[t];
        for (int c = 0; c < C_; ++c) a = fmaf(pooled[c], g1w[t * C_ + c], a);
        hidden[t] = 0.5f * a * (1.f + erff(a * 0.70710678118654752f));
    }
    __syncthreads();
    if (t == 0) {
        float z = g2b[0];
        for (int j = 0; j < 64; ++j) z = fmaf(hidden[j], g2w[j], z);
        const float gate = 1.f / (1.f + expf(-z));
        ws[OFF_GATE + b] = gate;
        out_gate[b] = gate;
    }
    for (int i = t; i < NH_ * 256; i += 256) ws[OFF_M + b * 1024 + i] = M0[i];
    for (int i = t; i < 64;        i += 256) ws[OFF_Z + b * 64 + i]   = Z0[i];
}

// ---------------------------------------------------------------------------
// K3: phi_k / v projections (LDS-staged weights, two passes over x), then
// XOR-swizzled staged outer-product reduction into M, Z.
// 512 threads, 1 pixel/thread, 512 px/block. LDS = 64KB (weights OR staging).
// ---------------------------------------------------------------------------
__global__ __launch_bounds__(512, 2) void k_mz(const float* __restrict__ x,
                                               float* __restrict__ ws) {
    __shared__ float lds[16384];   // 64KB
    const int b = blockIdx.y, t = threadIdx.x;
    const int px = blockIdx.x * 512 + t;
    const float* __restrict__ xb = x + (size_t)b * C_ * N_ + px;
    const float* __restrict__ wt = ws + OFF_WT;
    const float* __restrict__ sv = ws + OFF_S + b * C_;
    const float* __restrict__ tv = ws + OFF_T + b * C_;

    float ka[64], va[64];
    #pragma unroll
    for (int d = 0; d < 64; ++d) { ka[d] = 0.f; va[d] = 0.f; }

    // ---- pass 1: K projection, Wk -> LDS as [c][64] ----
    #pragma unroll
    for (int i = 0; i < 8; ++i) {
        const int lin4 = (t + i * 512) * 4;
        const int c = lin4 >> 6, d4 = lin4 & 63;
        *(float4*)(lds + lin4) = *(const float4*)(wt + c * 192 + d4);
    }
    __syncthreads();
    #pragma unroll 4
    for (int c = 0; c < C_; ++c) {
        const float xv = fmaf(xb[(size_t)c * N_], sv[c], tv[c]);
        const float4* wr = (const float4*)(lds + c * 64);
        #pragma unroll
        for (int j = 0; j < 16; ++j) {
            const float4 w = wr[j];
            ka[j*4+0] = fmaf(w.x, xv, ka[j*4+0]);
            ka[j*4+1] = fmaf(w.y, xv, ka[j*4+1]);
            ka[j*4+2] = fmaf(w.z, xv, ka[j*4+2]);
            ka[j*4+3] = fmaf(w.w, xv, ka[j*4+3]);
        }
    }
    __syncthreads();

    // ---- pass 2: V projection, Wv -> LDS ----
    #pragma unroll
    for (int i = 0; i < 8; ++i) {
        const int lin4 = (t + i * 512) * 4;
        const int c = lin4 >> 6, d4 = lin4 & 63;
        *(float4*)(lds + lin4) = *(const float4*)(wt + c * 192 + 64 + d4);
    }
    __syncthreads();
    #pragma unroll 4
    for (int c = 0; c < C_; ++c) {
        const float xv = fmaf(xb[(size_t)c * N_], sv[c], tv[c]);
        const float4* wr = (const float4*)(lds + c * 64);
        #pragma unroll
        for (int j = 0; j < 16; ++j) {
            const float4 w = wr[j];
            va[j*4+0] = fmaf(w.x, xv, va[j*4+0]);
            va[j*4+1] = fmaf(w.y, xv, va[j*4+1]);
            va[j*4+2] = fmaf(w.z, xv, va[j*4+2]);
            va[j*4+3] = fmaf(w.w, xv, va[j*4+3]);
        }
    }

    // phi_k = elu(k)+1
    #pragma unroll
    for (int d = 0; d < 64; ++d)
        ka[d] = ka[d] > 0.f ? ka[d] + 1.f : __expf(ka[d]);

    // ---- staged reduction: 4 sub-passes of 128 px, swizzled [64][128] f32 ----
    float* phi_s = lds;            // 32KB
    float* v_s   = lds + 8192;     // 32KB
    const int de = t & 255, dd = de >> 4, ee = de & 15, hg = t >> 8;
    const int rd0 = hg * 16 + dd,       re0 = hg * 16 + ee;
    const int rd1 = (hg + 2) * 16 + dd, re1 = (hg + 2) * 16 + ee;
    float m0 = 0.f, m1 = 0.f, zacc = 0.f;
    const int zrow = t & 63, zrep = (t >> 6) & 3;

    #pragma unroll
    for (int s = 0; s < 4; ++s) {
        __syncthreads();
        if ((t >> 7) == s) {
            const int tl = t & 127;
            const int hi = tl >> 2, lo = tl & 3;
            #pragma unroll
            for (int d = 0; d < 64; ++d) {
                const int a = d * 128 + (((hi ^ (d & 31)) << 2) | lo);
                phi_s[a] = ka[d];
                v_s[a]   = va[d];
            }
        }
        __syncthreads();
        #pragma unroll
        for (int hh = 0; hh < 2; ++hh) {
            const int rd = hh ? rd1 : rd0, re = hh ? re1 : re0;
            float acc = 0.f;
            #pragma unroll
            for (int p = 0; p < 32; ++p) {
                const float4 a  = *(const float4*)(phi_s + rd * 128 + ((p ^ (rd & 31)) << 2));
                const float4 bb = *(const float4*)(v_s   + re * 128 + ((p ^ (re & 31)) << 2));
                acc = fmaf(a.x, bb.x, acc);
                acc = fmaf(a.y, bb.y, acc);
                acc = fmaf(a.z, bb.z, acc);
                acc = fmaf(a.w, bb.w, acc);
            }
            if (hh) m1 += acc; else m0 += acc;
        }
        if (t < 256) {
            #pragma unroll
            for (int i = 0; i < 8; ++i) {
                const int p = zrep * 8 + i;
                const float4 a = *(const float4*)(phi_s + zrow * 128 + ((p ^ (zrow & 31)) << 2));
                zacc += a.x + a.y + a.z + a.w;
            }
        }
    }
    atomicAdd(&ws[OFF_M + b * 1024 + hg * 256 + dd * 16 + ee], m0);
    atomicAdd(&ws[OFF_M + b * 1024 + (hg + 2) * 256 + dd * 16 + ee], m1);
    if (t < 256) atomicAdd(&ws[OFF_Z + b * 64 + zrow], zacc);
}

// ---------------------------------------------------------------------------
// K4: phi_q (Wq in LDS) -> y via M/Z -> Wo (re-staged LDS) -> gated residual.
// 256 threads, 2 pixels/thread, 512 px/block. LDS = 64KB.
// ---------------------------------------------------------------------------
__global__ __launch_bounds__(256, 2) void k_out(const float* __restrict__ x,
        const float* __restrict__ Wo, const float* __restrict__ bo,
        float* __restrict__ out, const float* __restrict__ ws) {
    __shared__ float lds[16384];   // 64KB: Wq, then Wo, as [c][64]
    const int b = blockIdx.y, t = threadIdx.x;
    const int px = blockIdx.x * 512 + t * 2;
    const float* __restrict__ xb = x + (size_t)b * C_ * N_ + px;
    const float* __restrict__ wt = ws + OFF_WT;
    const float* __restrict__ sv = ws + OFF_S + b * C_;
    const float* __restrict__ tv = ws + OFF_T + b * C_;

    #pragma unroll
    for (int i = 0; i < 16; ++i) {
        const int lin4 = (t + i * 256) * 4;
        const int c = lin4 >> 6, o4 = lin4 & 63;
        *(float4*)(lds + lin4) = *(const float4*)(wt + c * 192 + 128 + o4);
    }
    __syncthreads();

    float q0[64], q1[64];
    #pragma unroll
    for (int d = 0; d < 64; ++d) { q0[d] = 0.f; q1[d] = 0.f; }

    #pragma unroll 2
    for (int c = 0; c < C_; ++c) {
        const float2 xv = *(const float2*)(xb + (size_t)c * N_);
        const float a0 = fmaf(xv.x, sv[c], tv[c]);
        const float a1 = fmaf(xv.y, sv[c], tv[c]);
        const float4* wr = (const float4*)(lds + c * 64);
        #pragma unroll
        for (int j = 0; j < 16; ++j) {
            const float4 w = wr[j];
            q0[j*4+0] = fmaf(w.x, a0, q0[j*4+0]);  q1[j*4+0] = fmaf(w.x, a1, q1[j*4+0]);
            q0[j*4+1] = fmaf(w.y, a0, q0[j*4+1]);  q1[j*4+1] = fmaf(w.y, a1, q1[j*4+1]);
            q0[j*4+2] = fmaf(w.z, a0, q0[j*4+2]);  q1[j*4+2] = fmaf(w.z, a1, q1[j*4+2]);
            q0[j*4+3] = fmaf(w.w, a0, q0[j*4+3]);  q1[j*4+3] = fmaf(w.w, a1, q1[j*4+3]);
        }
    }
    #pragma unroll
    for (int d = 0; d < 64; ++d) {
        q0[d] = q0[d] > 0.f ? q0[d] + 1.f : __expf(q0[d]);   // phi_q
        q1[d] = q1[d] > 0.f ? q1[d] + 1.f : __expf(q1[d]);
    }

    // y = (M^T phi_q) / max(Z.phi_q, 1e-4), written back over q0/q1
    const float* __restrict__ Mb = ws + OFF_M + b * 1024;
    const float* __restrict__ Zb = ws + OFF_Z + b * 64;
    #pragma unroll
    for (int h = 0; h < NH_; ++h) {
        float t0[16], t1[16];
        #pragma unroll
        for (int e = 0; e < 16; ++e) { t0[e] = 0.f; t1[e] = 0.f; }
        float d0 = 0.f, d1 = 0.f;
        #pragma unroll
        for (int d = 0; d < 16; ++d) {
            const float qv0 = q0[h * 16 + d], qv1 = q1[h * 16 + d];
            const float zc = Zb[h * 16 + d];
            d0 = fmaf(zc, qv0, d0);
            d1 = fmaf(zc, qv1, d1);
            const float* __restrict__ Mr = Mb + h * 256 + d * 16;
            #pragma unroll
            for (int e = 0; e < 16; ++e) {
                t0[e] = fmaf(Mr[e], qv0, t0[e]);
                t1[e] = fmaf(Mr[e], qv1, t1[e]);
            }
        }
        const float r0 = 1.f / fmaxf(d0, 1e-4f);
        const float r1 = 1.f / fmaxf(d1, 1e-4f);
        #pragma unroll
        for (int e = 0; e < 16; ++e) {
            q0[h * 16 + e] = t0[e] * r0;
            q1[h * 16 + e] = t1[e] * r1;
        }
    }

    __syncthreads();
    #pragma unroll
    for (int i = 0; i < 16; ++i) {
        const int lin4 = (t + i * 256) * 4;
        *(float4*)(lds + lin4) = *(const float4*)(Wo + lin4);
    }
    __syncthreads();

    const float gate = ws[OFF_GATE + b];
    float* __restrict__ ob = out + (size_t)b * C_ * N_ + px;
    #pragma unroll 2
    for (int c = 0; c < C_; ++c) {
        float acc0 = bo[c], acc1 = bo[c];
        const float4* wr = (const float4*)(lds + c * 64);
        #pragma unroll
        for (int j = 0; j < 16; ++j) {
            const float4 w = wr[j];
            acc0 = fmaf(w.x, q0[j*4+0], acc0);  acc1 = fmaf(w.x, q1[j*4+0], acc1);
            acc0 = fmaf(w.y, q0[j*4+1], acc0);  acc1 = fmaf(w.y, q1[j*4+1], acc1);
            acc0 = fmaf(w.z, q0[j*4+2], acc0);  acc1 = fmaf(w.z, q1[j*4+2], acc1);
            acc0 = fmaf(w.w, q0[j*4+3], acc0);  acc1 = fmaf(w.w, q1[j*4+3], acc1);
        }
        const float2 xr = *(const float2*)(xb + (size_t)c * N_);
        float2 o;
        o.x = fmaf(gate, acc0, xr.x);
        o.y = fmaf(gate, acc1, xr.y);
        *(float2*)(ob + (size_t)c * N_) = o;
    }
}

// ---------------------------------------------------------------------------
extern "C" void kernel_launch(void* const* d_in, const int* in_sizes, int n_in,
                              void* d_out, int out_size, void* d_ws, size_t ws_size,
                              hipStream_t stream) {
    const float* x   = (const float*)d_in[0];
    const float* gnw = (const float*)d_in[1];
    const float* gnb = (const float*)d_in[2];
    const float* Wk  = (const float*)d_in[3];
    const float* Wv  = (const float*)d_in[4];
    const float* Wq  = (const float*)d_in[5];
    const float* Wo  = (const float*)d_in[6];
    const float* bo  = (const float*)d_in[7];
    const float* M0  = (const float*)d_in[8];
    const float* Z0  = (const float*)d_in[9];
    const float* g1w = (const float*)d_in[10];
    const float* g1b = (const float*)d_in[11];
    const float* g2w = (const float*)d_in[12];
    const float* g2b = (const float*)d_in[13];
    float* out = (float*)d_out;
    float* ws  = (float*)d_ws;

    hipLaunchKernelGGL(k_stats, dim3(B_ * C_), dim3(256), 0, stream, x, ws);
    hipLaunchKernelGGL(k_tr,    dim3(C_),      dim3(192), 0, stream, Wk, Wv, Wq, ws);
    hipLaunchKernelGGL(k_prep,  dim3(B_),      dim3(256), 0, stream,
                       gnw, gnb, M0, Z0, g1w, g1b, g2w, g2b, ws,
                       out + (size_t)B_ * C_ * N_);
    hipLaunchKernelGGL(k_mz,    dim3(N_ / 512, B_), dim3(512), 0, stream, x, ws);
    hipLaunchKernelGGL(k_out,   dim3(N_ / 512, B_), dim3(256), 0, stream,
                       x, Wo, bo, out, ws);
}

// Round 5
// 413.959 us; speedup vs baseline: 6.8772x; 6.8772x over previous
//
#include <hip/hip_runtime.h>
#include <math.h>

typedef __attribute__((ext_vector_type(8))) short short8b;   // 8 bf16 = 4 VGPR
typedef __attribute__((ext_vector_type(4))) float f32x4;

#define B_   16
#define C_   256
#define N_   16384      // H*W
#define NH_  4
#define G_   8
#define CPG_ 32

// Workspace layout (float offsets) — total 50192 floats (~196 KB), well below
// the empirically proven-safe ws size (~332 KB used by an earlier passing run).
#define OFF_S    0        // [B][C] folded GN scale   (k_stats writes SUM here first)
#define OFF_T    4096     // [B][C] folded GN shift   (k_stats writes SQ here first)
#define OFF_SUM  OFF_S
#define OFF_SQ   OFF_T
#define OFF_M    8192     // [B][4][16][16] f32
#define OFF_Z    24576    // [B][64] f32
#define OFF_GATE 25600    // [B]
#define OFF_WKVQ 25616    // bf16 [192][256] (24576 floats)

static __device__ inline unsigned short bf16u(float f) {
    unsigned int u = __float_as_uint(f);
    return (unsigned short)((u + 0x7FFFu + ((u >> 16) & 1u)) >> 16);   // RNE
}
static __device__ inline float ubf(unsigned short u) {
    return __uint_as_float(((unsigned int)u) << 16);
}

// ---------------------------------------------------------------------------
// K1: per-(b,c) sum and sumsq over pixels. One block per (b,c).
// ---------------------------------------------------------------------------
__global__ __launch_bounds__(256) void k_stats(const float* __restrict__ x,
                                               float* __restrict__ ws) {
    const int bc = blockIdx.x;
    const float4* p4 = (const float4*)(x + (size_t)bc * N_);
    float s = 0.f, q = 0.f;
    #pragma unroll 4
    for (int i = threadIdx.x; i < N_ / 4; i += 256) {
        float4 v = p4[i];
        s += v.x + v.y + v.z + v.w;
        q += v.x * v.x + v.y * v.y + v.z * v.z + v.w * v.w;
    }
    #pragma unroll
    for (int o = 32; o > 0; o >>= 1) {
        s += __shfl_down(s, o);
        q += __shfl_down(q, o);
    }
    __shared__ float ls[4], lq[4];
    const int wid = threadIdx.x >> 6, lane = threadIdx.x & 63;
    if (lane == 0) { ls[wid] = s; lq[wid] = q; }
    __syncthreads();
    if (threadIdx.x == 0) {
        ws[OFF_SUM + bc] = ls[0] + ls[1] + ls[2] + ls[3];
        ws[OFF_SQ  + bc] = lq[0] + lq[1] + lq[2] + lq[3];
    }
}

// ---------------------------------------------------------------------------
// K_cvtw: Wk|Wv|Wq -> bf16 table [192][256], row-major (K contiguous).
// ---------------------------------------------------------------------------
__global__ __launch_bounds__(256) void k_cvtw(const float* __restrict__ Wk,
        const float* __restrict__ Wv, const float* __restrict__ Wq,
        float* __restrict__ ws) {
    unsigned short* wkvq = (unsigned short*)(ws + OFF_WKVQ);
    const int r = blockIdx.x, t = threadIdx.x;
    const float* src = r < 64 ? Wk + r * C_
                     : r < 128 ? Wv + (r - 64) * C_
                     : Wq + (r - 128) * C_;
    wkvq[r * 256 + t] = bf16u(src[t]);
}

// ---------------------------------------------------------------------------
// K2: per-batch prep — GN fold (in-place over SUM/SQ), gate MLP, M/Z init.
// ---------------------------------------------------------------------------
__global__ __launch_bounds__(256) void k_prep(
        const float* __restrict__ gnw, const float* __restrict__ gnb,
        const float* __restrict__ M0,  const float* __restrict__ Z0,
        const float* __restrict__ g1w, const float* __restrict__ g1b,
        const float* __restrict__ g2w, const float* __restrict__ g2b,
        float* __restrict__ ws, float* __restrict__ out_gate) {
    const int b = blockIdx.x, t = threadIdx.x;
    __shared__ float mu[G_], rs[G_];
    __shared__ float pooled[C_];
    __shared__ float hidden[64];

    if (t < G_) {
        float S = 0.f, Q = 0.f;
        for (int c = t * CPG_; c < (t + 1) * CPG_; ++c) {
            S += ws[OFF_SUM + b * C_ + c];
            Q += ws[OFF_SQ  + b * C_ + c];
        }
        const float cnt = (float)(CPG_ * N_);
        const float m = S / cnt;
        const float var = Q / cnt - m * m;
        mu[t] = m;
        rs[t] = rsqrtf(var + 1e-5f);
    }
    __syncthreads();
    {
        const int c = t;
        const int g = c / CPG_;
        const float sumc = ws[OFF_SUM + b * C_ + c];   // read BEFORE in-place overwrite
        const float sc = rs[g] * gnw[c];
        const float tc = gnb[c] - mu[g] * sc;
        ws[OFF_S + b * C_ + c] = sc;
        ws[OFF_T + b * C_ + c] = tc;
        pooled[c] = fmaf(sumc * (1.f / (float)N_), sc, tc);
    }
    __syncthreads();
    if (t < 64) {
        float a = g1b[t];
        for (int c = 0; c < C_; ++c) a = fmaf(pooled[c], g1w[t * C_ + c], a);
        hidden[t] = 0.5f * a * (1.f + erff(a * 0.70710678118654752f));
    }
    __syncthreads();
    if (t == 0) {
        float z = g2b[0];
        for (int j = 0; j < 64; ++j) z = fmaf(hidden[j], g2w[j], z);
        const float gate = 1.f / (1.f + expf(-z));
        ws[OFF_GATE + b] = gate;
        out_gate[b] = gate;
    }
    for (int i = t; i < NH_ * 256; i += 256) ws[OFF_M + b * 1024 + i] = M0[i];
    for (int i = t; i < 64;        i += 256) ws[OFF_Z + b * 64 + i]   = Z0[i];
}

// ---------------------------------------------------------------------------
// K3 (MFMA): K|V projection GEMM. Per block: [128 rows][128 px], K=256.
// phi(elu+1) applied to K rows. Output bf16 -> d_out overlay (consumed by
// k_mz2 before k_out3 overwrites d_out; stream-ordered, rewritten per call).
// ---------------------------------------------------------------------------
__global__ __launch_bounds__(256) void k_proj(const float* __restrict__ x,
        const float* __restrict__ ws, unsigned short* __restrict__ kv_out) {
    __shared__ __align__(16) char lds[128 * 80 + 128 * 80];   // w_s | x_s
    char* w_s = lds;
    char* x_s = lds + 128 * 80;
    const int b = blockIdx.y, px0 = blockIdx.x * 128;
    const int t = threadIdx.x, w = t >> 6, l = t & 63;
    const float* __restrict__ sv = ws + OFF_S + b * C_;
    const float* __restrict__ tv = ws + OFF_T + b * C_;
    const unsigned int* __restrict__ wkvq32 = (const unsigned int*)(ws + OFF_WKVQ);
    const float* __restrict__ xb = x + (size_t)b * C_ * N_ + px0;

    f32x4 acc[2][8];
    #pragma unroll
    for (int i = 0; i < 2; ++i)
        #pragma unroll
        for (int j = 0; j < 8; ++j) acc[i][j] = (f32x4){0.f, 0.f, 0.f, 0.f};

    for (int ks = 0; ks < 8; ++ks) {
        __syncthreads();
        // stage W chunk [128 rows][32 k] bf16 (2048 dwords)
        #pragma unroll
        for (int i = 0; i < 8; ++i) {
            const int e2 = t + 256 * i;
            const int row = e2 >> 4, kp = e2 & 15;
            *(unsigned int*)(w_s + row * 80 + kp * 4) =
                wkvq32[row * 128 + ks * 16 + kp];
        }
        // stage x chunk transposed -> [px][32 c] bf16, GN folded
        {
            const int px = t & 127, half = t >> 7;
            #pragma unroll
            for (int i = 0; i < 8; ++i) {
                const int lc = half * 16 + i * 2;
                const int c = ks * 32 + lc;
                const float a0 = fmaf(xb[(size_t)c * N_ + px],       sv[c],     tv[c]);
                const float a1 = fmaf(xb[(size_t)(c + 1) * N_ + px], sv[c + 1], tv[c + 1]);
                *(unsigned int*)(x_s + px * 80 + lc * 2) =
                    ((unsigned int)bf16u(a1) << 16) | bf16u(a0);
            }
        }
        __syncthreads();
        short8b bfr[8];
        #pragma unroll
        for (int ct = 0; ct < 8; ++ct)
            bfr[ct] = *(const short8b*)(x_s + (ct * 16 + (l & 15)) * 80 + (l >> 4) * 16);
        #pragma unroll
        for (int rt = 0; rt < 2; ++rt) {
            const int row = w * 32 + rt * 16 + (l & 15);
            const short8b af = *(const short8b*)(w_s + row * 80 + (l >> 4) * 16);
            #pragma unroll
            for (int ct = 0; ct < 8; ++ct)
                acc[rt][ct] = __builtin_amdgcn_mfma_f32_16x16x32_bf16(
                                  af, bfr[ct], acc[rt][ct], 0, 0, 0);
        }
    }
    #pragma unroll
    for (int rt = 0; rt < 2; ++rt) {
        const int base = w * 32 + rt * 16;
        const bool do_elu = base < 64;                       // phi_k rows
        #pragma unroll
        for (int ct = 0; ct < 8; ++ct) {
            const int px = px0 + ct * 16 + (l & 15);
            #pragma unroll
            for (int r = 0; r < 4; ++r) {
                const int row = base + (l >> 4) * 4 + r;
                float v = acc[rt][ct][r];
                if (do_elu) v = v > 0.f ? v + 1.f : __expf(v);
                kv_out[((size_t)b * 128 + row) * N_ + px] = bf16u(v);
            }
        }
    }
}

// ---------------------------------------------------------------------------
// K4 (MFMA): M += phik·v^T over pixels (GEMM with K=px), Z += row-sums.
// grid (16, B); each block reduces 1024 px in 8 stages of 128.
// ---------------------------------------------------------------------------
__global__ __launch_bounds__(256) void k_mz2(const unsigned short* __restrict__ kv,
                                             float* __restrict__ ws) {
    __shared__ __align__(16) unsigned short kv_s[128][136];   // 34816 B
    const int b = blockIdx.y, t = threadIdx.x, w = t >> 6, l = t & 63;
    const int zrow = t >> 2, zq = t & 3;
    f32x4 accm = (f32x4){0.f, 0.f, 0.f, 0.f};
    float z = 0.f;

    for (int st = 0; st < 8; ++st) {
        const int px0 = (blockIdx.x * 8 + st) * 128;
        __syncthreads();
        #pragma unroll
        for (int i = 0; i < 32; ++i) {
            const int e2 = t + 256 * i;                      // 8192 dwords
            const int row = e2 >> 6, pp = (e2 & 63) * 2;
            *(unsigned int*)&kv_s[row][pp] =
                *(const unsigned int*)&kv[((size_t)b * 128 + row) * N_ + px0 + pp];
        }
        __syncthreads();
        #pragma unroll
        for (int kc = 0; kc < 4; ++kc) {
            const short8b af = *(const short8b*)((const char*)&kv_s[w * 16 + (l & 15)][0]
                                                 + kc * 64 + (l >> 4) * 16);
            const short8b bf = *(const short8b*)((const char*)&kv_s[64 + w * 16 + (l & 15)][0]
                                                 + kc * 64 + (l >> 4) * 16);
            accm = __builtin_amdgcn_mfma_f32_16x16x32_bf16(af, bf, accm, 0, 0, 0);
        }
        #pragma unroll
        for (int j = 0; j < 16; ++j) {
            const unsigned int u = *(const unsigned int*)&kv_s[zrow][zq * 32 + j * 2];
            z += ubf((unsigned short)u) + ubf((unsigned short)(u >> 16));
        }
    }
    #pragma unroll
    for (int r = 0; r < 4; ++r) {
        const int d = (l >> 4) * 4 + r, e = l & 15;
        atomicAdd(&ws[OFF_M + b * 1024 + w * 256 + d * 16 + e], accm[r]);
    }
    atomicAdd(&ws[OFF_Z + b * 64 + zrow], z);
}

// ---------------------------------------------------------------------------
// K5 (MFMA): phi_q GEMM (K=256) -> in-wave den + psi -> W2 GEMM (K=64) ->
// epilogue. W2 = Wo·M^T computed IN-KERNEL from Wo (global, L2-resident)
// and M (4KB LDS) — no global W2 buffer, ws stays small.
// ---------------------------------------------------------------------------
__global__ __launch_bounds__(256) void k_out3(const float* __restrict__ x,
        const float* __restrict__ Wo, const float* __restrict__ bo,
        const float* __restrict__ ws, float* __restrict__ out) {
    __shared__ __align__(16) char lds[71680];
    char*  w2_s = lds;                      // [256][144B] (128 data + pad, pad unread)
    char*  pq_s = lds + 36864;              // [128][144B] psi (prologue: m_s scratch)
    char*  wq_s = lds + 55296;              // [64][80B]
    char*  x_s  = lds + 60416;              // [128][80B]
    float* bo_s = (float*)(lds + 70656);    // [256]

    const int b = blockIdx.y, px0 = blockIdx.x * 128;
    const int t = threadIdx.x, w = t >> 6, l = t & 63;
    const float* __restrict__ sv = ws + OFF_S + b * C_;
    const float* __restrict__ tv = ws + OFF_T + b * C_;
    const unsigned int* __restrict__ wkvq32 = (const unsigned int*)(ws + OFF_WKVQ);
    const float* __restrict__ xb = x + (size_t)b * C_ * N_ + px0;

    bo_s[t] = bo[t];
    float* m_s = (float*)pq_s;               // 4 KB scratch inside pq_s region
    for (int i = t; i < 1024; i += 256) m_s[i] = ws[OFF_M + b * 1024 + i];
    float zr[4];
    #pragma unroll
    for (int r = 0; r < 4; ++r)
        zr[r] = ws[OFF_Z + b * 64 + w * 16 + (l >> 4) * 4 + r];

    // ---- phase 1: phi_q GEMM, wave w -> head w ----
    f32x4 accq[8];
    #pragma unroll
    for (int j = 0; j < 8; ++j) accq[j] = (f32x4){0.f, 0.f, 0.f, 0.f};

    for (int ks = 0; ks < 8; ++ks) {
        __syncthreads();     // first iteration also covers m_s/bo_s staging
        #pragma unroll
        for (int i = 0; i < 4; ++i) {
            const int e2 = t + 256 * i;                      // 1024 dwords
            const int row = e2 >> 4, kp = e2 & 15;
            *(unsigned int*)(wq_s + row * 80 + kp * 4) =
                wkvq32[(128 + row) * 128 + ks * 16 + kp];
        }
        {
            const int px = t & 127, half = t >> 7;
            #pragma unroll
            for (int i = 0; i < 8; ++i) {
                const int lc = half * 16 + i * 2;
                const int c = ks * 32 + lc;
                const float a0 = fmaf(xb[(size_t)c * N_ + px],       sv[c],     tv[c]);
                const float a1 = fmaf(xb[(size_t)(c + 1) * N_ + px], sv[c + 1], tv[c + 1]);
                *(unsigned int*)(x_s + px * 80 + lc * 2) =
                    ((unsigned int)bf16u(a1) << 16) | bf16u(a0);
            }
        }
        __syncthreads();
        const short8b af = *(const short8b*)(wq_s + (w * 16 + (l & 15)) * 80 + (l >> 4) * 16);
        #pragma unroll
        for (int ct = 0; ct < 8; ++ct) {
            const short8b bfr = *(const short8b*)(x_s + (ct * 16 + (l & 15)) * 80 + (l >> 4) * 16);
            accq[ct] = __builtin_amdgcn_mfma_f32_16x16x32_bf16(af, bfr, accq[ct], 0, 0, 0);
        }
    }

    // ---- W2 = Wo·M^T: thread t = channel c; m_s reads are LDS broadcasts ----
    #pragma unroll
    for (int h = 0; h < NH_; ++h) {
        float wrow[16];
        #pragma unroll
        for (int j = 0; j < 4; ++j)
            *(float4*)&wrow[j * 4] = *(const float4*)&Wo[t * 64 + h * 16 + j * 4];
        #pragma unroll
        for (int d = 0; d < 16; ++d) {
            float a = 0.f;
            #pragma unroll
            for (int e = 0; e < 16; ++e)
                a = fmaf(wrow[e], m_s[h * 256 + d * 16 + e], a);
            *(unsigned short*)(w2_s + t * 144 + (h * 16 + d) * 2) = bf16u(a);
        }
    }
    __syncthreads();   // all m_s reads done before psi overwrites pq_s region

    // ---- phi, per-pixel den (in-wave shuffle), psi -> pq_s transposed ----
    #pragma unroll
    for (int ct = 0; ct < 8; ++ct) {
        float p[4];
        #pragma unroll
        for (int r = 0; r < 4; ++r) {
            const float v = accq[ct][r];
            p[r] = v > 0.f ? v + 1.f : __expf(v);
        }
        float dp = 0.f;
        #pragma unroll
        for (int r = 0; r < 4; ++r) dp = fmaf(zr[r], p[r], dp);
        dp += __shfl_xor(dp, 16);
        dp += __shfl_xor(dp, 32);
        const float rd = 1.f / fmaxf(dp, 1e-4f);
        const int px = ct * 16 + (l & 15);
        #pragma unroll
        for (int r = 0; r < 4; ++r) {
            const int e = w * 16 + (l >> 4) * 4 + r;
            *(unsigned short*)(pq_s + px * 144 + e * 2) = bf16u(p[r] * rd);
        }
    }
    __syncthreads();   // psi + W2 both visible to all waves

    // ---- phase 3: out = W2 · psi (K=64), wave w -> rows w*64..+64 ----
    f32x4 acc[4][8];
    #pragma unroll
    for (int i = 0; i < 4; ++i)
        #pragma unroll
        for (int j = 0; j < 8; ++j) acc[i][j] = (f32x4){0.f, 0.f, 0.f, 0.f};
    #pragma unroll
    for (int ksi = 0; ksi < 2; ++ksi) {
        short8b bfr[8];
        #pragma unroll
        for (int ct = 0; ct < 8; ++ct)
            bfr[ct] = *(const short8b*)(pq_s + (ct * 16 + (l & 15)) * 144
                                        + ksi * 64 + (l >> 4) * 16);
        #pragma unroll
        for (int rt = 0; rt < 4; ++rt) {
            const int row = w * 64 + rt * 16 + (l & 15);
            const short8b af = *(const short8b*)(w2_s + row * 144 + ksi * 64 + (l >> 4) * 16);
            #pragma unroll
            for (int ct = 0; ct < 8; ++ct)
                acc[rt][ct] = __builtin_amdgcn_mfma_f32_16x16x32_bf16(
                                  af, bfr[ct], acc[rt][ct], 0, 0, 0);
        }
    }

    // ---- epilogue: out = x + gate*(acc + bo) ----
    const float gate = ws[OFF_GATE + b];
    const float* __restrict__ xr = x + (size_t)b * C_ * N_;
    float* __restrict__ ob = out + (size_t)b * C_ * N_;
    #pragma unroll
    for (int rt = 0; rt < 4; ++rt) {
        #pragma unroll
        for (int ct = 0; ct < 8; ++ct) {
            const int px = px0 + ct * 16 + (l & 15);
            #pragma unroll
            for (int r = 0; r < 4; ++r) {
                const int row = w * 64 + rt * 16 + (l >> 4) * 4 + r;
                const size_t off = (size_t)row * N_ + px;
                ob[off] = fmaf(gate, acc[rt][ct][r] + bo_s[row], xr[off]);
            }
        }
    }
}

// ---------------------------------------------------------------------------
extern "C" void kernel_launch(void* const* d_in, const int* in_sizes, int n_in,
                              void* d_out, int out_size, void* d_ws, size_t ws_size,
                              hipStream_t stream) {
    const float* x   = (const float*)d_in[0];
    const float* gnw = (const float*)d_in[1];
    const float* gnb = (const float*)d_in[2];
    const float* Wk  = (const float*)d_in[3];
    const float* Wv  = (const float*)d_in[4];
    const float* Wq  = (const float*)d_in[5];
    const float* Wo  = (const float*)d_in[6];
    const float* bo  = (const float*)d_in[7];
    const float* M0  = (const float*)d_in[8];
    const float* Z0  = (const float*)d_in[9];
    const float* g1w = (const float*)d_in[10];
    const float* g1b = (const float*)d_in[11];
    const float* g2w = (const float*)d_in[12];
    const float* g2b = (const float*)d_in[13];
    float* out = (float*)d_out;
    float* ws  = (float*)d_ws;
    // K|V bf16 overlay in d_out: written by k_proj, read by k_mz2, then fully
    // overwritten by k_out3 — all stream-ordered and rewritten every call.
    unsigned short* kv_overlay = (unsigned short*)d_out;

    hipLaunchKernelGGL(k_stats, dim3(B_ * C_), dim3(256), 0, stream, x, ws);
    hipLaunchKernelGGL(k_cvtw,  dim3(192),     dim3(256), 0, stream, Wk, Wv, Wq, ws);
    hipLaunchKernelGGL(k_prep,  dim3(B_),      dim3(256), 0, stream,
                       gnw, gnb, M0, Z0, g1w, g1b, g2w, g2b, ws,
                       out + (size_t)B_ * C_ * N_);
    hipLaunchKernelGGL(k_proj,  dim3(N_ / 128, B_), dim3(256), 0, stream,
                       x, ws, kv_overlay);
    hipLaunchKernelGGL(k_mz2,   dim3(16, B_),  dim3(256), 0, stream, kv_overlay, ws);
    hipLaunchKernelGGL(k_out3,  dim3(N_ / 128, B_), dim3(256), 0, stream,
                       x, Wo, bo, ws, out);
}

// Round 6
// 403.072 us; speedup vs baseline: 7.0630x; 1.0270x over previous
//
#include <hip/hip_runtime.h>
#include <math.h>

typedef __attribute__((ext_vector_type(8))) short short8b;   // 8 bf16 = 4 VGPR
typedef __attribute__((ext_vector_type(4))) float f32x4;

#define B_   16
#define C_   256
#define N_   16384      // H*W
#define NH_  4
#define G_   8
#define CPG_ 32

// Workspace layout (float offsets) — total ~196 KB (proven-safe < 332 KB)
#define OFF_S    0        // [B][C] folded GN scale   (k_stats writes SUM here first)
#define OFF_T    4096     // [B][C] folded GN shift   (k_stats writes SQ here first)
#define OFF_SUM  OFF_S
#define OFF_SQ   OFF_T
#define OFF_M    8192     // [B][4][16][16] f32
#define OFF_Z    24576    // [B][64] f32
#define OFF_GATE 25600    // [B]
#define OFF_WKVQ 25616    // bf16 [192][256] (24576 floats)

static __device__ inline unsigned short bf16u(float f) {
    unsigned int u = __float_as_uint(f);
    return (unsigned short)((u + 0x7FFFu + ((u >> 16) & 1u)) >> 16);   // RNE
}
static __device__ inline float ubf(unsigned short u) {
    return __uint_as_float(((unsigned int)u) << 16);
}

// ---------------------------------------------------------------------------
// K1: per-(b,c) sum and sumsq over pixels. One block per (b,c).
// ---------------------------------------------------------------------------
__global__ __launch_bounds__(256) void k_stats(const float* __restrict__ x,
                                               float* __restrict__ ws) {
    const int bc = blockIdx.x;
    const float4* p4 = (const float4*)(x + (size_t)bc * N_);
    float s = 0.f, q = 0.f;
    #pragma unroll 4
    for (int i = threadIdx.x; i < N_ / 4; i += 256) {
        float4 v = p4[i];
        s += v.x + v.y + v.z + v.w;
        q += v.x * v.x + v.y * v.y + v.z * v.z + v.w * v.w;
    }
    #pragma unroll
    for (int o = 32; o > 0; o >>= 1) {
        s += __shfl_down(s, o);
        q += __shfl_down(q, o);
    }
    __shared__ float ls[4], lq[4];
    const int wid = threadIdx.x >> 6, lane = threadIdx.x & 63;
    if (lane == 0) { ls[wid] = s; lq[wid] = q; }
    __syncthreads();
    if (threadIdx.x == 0) {
        ws[OFF_SUM + bc] = ls[0] + ls[1] + ls[2] + ls[3];
        ws[OFF_SQ  + bc] = lq[0] + lq[1] + lq[2] + lq[3];
    }
}

// ---------------------------------------------------------------------------
// K_cvtw: Wk|Wv|Wq -> bf16 table [192][256], row-major (K contiguous).
// ---------------------------------------------------------------------------
__global__ __launch_bounds__(256) void k_cvtw(const float* __restrict__ Wk,
        const float* __restrict__ Wv, const float* __restrict__ Wq,
        float* __restrict__ ws) {
    unsigned short* wkvq = (unsigned short*)(ws + OFF_WKVQ);
    const int r = blockIdx.x, t = threadIdx.x;
    const float* src = r < 64 ? Wk + r * C_
                     : r < 128 ? Wv + (r - 64) * C_
                     : Wq + (r - 128) * C_;
    wkvq[r * 256 + t] = bf16u(src[t]);
}

// ---------------------------------------------------------------------------
// K2: per-batch prep — GN fold (in-place over SUM/SQ), gate MLP, M/Z init.
// ---------------------------------------------------------------------------
__global__ __launch_bounds__(256) void k_prep(
        const float* __restrict__ gnw, const float* __restrict__ gnb,
        const float* __restrict__ M0,  const float* __restrict__ Z0,
        const float* __restrict__ g1w, const float* __restrict__ g1b,
        const float* __restrict__ g2w, const float* __restrict__ g2b,
        float* __restrict__ ws, float* __restrict__ out_gate) {
    const int b = blockIdx.x, t = threadIdx.x;
    __shared__ float mu[G_], rs[G_];
    __shared__ float pooled[C_];
    __shared__ float hidden[64];

    if (t < G_) {
        float S = 0.f, Q = 0.f;
        for (int c = t * CPG_; c < (t + 1) * CPG_; ++c) {
            S += ws[OFF_SUM + b * C_ + c];
            Q += ws[OFF_SQ  + b * C_ + c];
        }
        const float cnt = (float)(CPG_ * N_);
        const float m = S / cnt;
        const float var = Q / cnt - m * m;
        mu[t] = m;
        rs[t] = rsqrtf(var + 1e-5f);
    }
    __syncthreads();
    {
        const int c = t;
        const int g = c / CPG_;
        const float sumc = ws[OFF_SUM + b * C_ + c];   // read BEFORE in-place overwrite
        const float sc = rs[g] * gnw[c];
        const float tc = gnb[c] - mu[g] * sc;
        ws[OFF_S + b * C_ + c] = sc;
        ws[OFF_T + b * C_ + c] = tc;
        pooled[c] = fmaf(sumc * (1.f / (float)N_), sc, tc);
    }
    __syncthreads();
    if (t < 64) {
        float a = g1b[t];
        for (int c = 0; c < C_; ++c) a = fmaf(pooled[c], g1w[t * C_ + c], a);
        hidden[t] = 0.5f * a * (1.f + erff(a * 0.70710678118654752f));
    }
    __syncthreads();
    if (t == 0) {
        float z = g2b[0];
        for (int j = 0; j < 64; ++j) z = fmaf(hidden[j], g2w[j], z);
        const float gate = 1.f / (1.f + expf(-z));
        ws[OFF_GATE + b] = gate;
        out_gate[b] = gate;
    }
    for (int i = t; i < NH_ * 256; i += 256) ws[OFF_M + b * 1024 + i] = M0[i];
    for (int i = t; i < 64;        i += 256) ws[OFF_Z + b * 64 + i]   = Z0[i];
}

// ---------------------------------------------------------------------------
// K3 (MFMA): K|V projection GEMM. Per block: [128 rows][128 px], K=256.
// (unchanged from round 5 — proven)
// ---------------------------------------------------------------------------
__global__ __launch_bounds__(256) void k_proj(const float* __restrict__ x,
        const float* __restrict__ ws, unsigned short* __restrict__ kv_out) {
    __shared__ __align__(16) char lds[128 * 80 + 128 * 80];   // w_s | x_s
    char* w_s = lds;
    char* x_s = lds + 128 * 80;
    const int b = blockIdx.y, px0 = blockIdx.x * 128;
    const int t = threadIdx.x, w = t >> 6, l = t & 63;
    const float* __restrict__ sv = ws + OFF_S + b * C_;
    const float* __restrict__ tv = ws + OFF_T + b * C_;
    const unsigned int* __restrict__ wkvq32 = (const unsigned int*)(ws + OFF_WKVQ);
    const float* __restrict__ xb = x + (size_t)b * C_ * N_ + px0;

    f32x4 acc[2][8];
    #pragma unroll
    for (int i = 0; i < 2; ++i)
        #pragma unroll
        for (int j = 0; j < 8; ++j) acc[i][j] = (f32x4){0.f, 0.f, 0.f, 0.f};

    for (int ks = 0; ks < 8; ++ks) {
        __syncthreads();
        #pragma unroll
        for (int i = 0; i < 8; ++i) {
            const int e2 = t + 256 * i;
            const int row = e2 >> 4, kp = e2 & 15;
            *(unsigned int*)(w_s + row * 80 + kp * 4) =
                wkvq32[row * 128 + ks * 16 + kp];
        }
        {
            const int px = t & 127, half = t >> 7;
            #pragma unroll
            for (int i = 0; i < 8; ++i) {
                const int lc = half * 16 + i * 2;
                const int c = ks * 32 + lc;
                const float a0 = fmaf(xb[(size_t)c * N_ + px],       sv[c],     tv[c]);
                const float a1 = fmaf(xb[(size_t)(c + 1) * N_ + px], sv[c + 1], tv[c + 1]);
                *(unsigned int*)(x_s + px * 80 + lc * 2) =
                    ((unsigned int)bf16u(a1) << 16) | bf16u(a0);
            }
        }
        __syncthreads();
        short8b bfr[8];
        #pragma unroll
        for (int ct = 0; ct < 8; ++ct)
            bfr[ct] = *(const short8b*)(x_s + (ct * 16 + (l & 15)) * 80 + (l >> 4) * 16);
        #pragma unroll
        for (int rt = 0; rt < 2; ++rt) {
            const int row = w * 32 + rt * 16 + (l & 15);
            const short8b af = *(const short8b*)(w_s + row * 80 + (l >> 4) * 16);
            #pragma unroll
            for (int ct = 0; ct < 8; ++ct)
                acc[rt][ct] = __builtin_amdgcn_mfma_f32_16x16x32_bf16(
                                  af, bfr[ct], acc[rt][ct], 0, 0, 0);
        }
    }
    #pragma unroll
    for (int rt = 0; rt < 2; ++rt) {
        const int base = w * 32 + rt * 16;
        const bool do_elu = base < 64;                       // phi_k rows
        #pragma unroll
        for (int ct = 0; ct < 8; ++ct) {
            const int px = px0 + ct * 16 + (l & 15);
            #pragma unroll
            for (int r = 0; r < 4; ++r) {
                const int row = base + (l >> 4) * 4 + r;
                float v = acc[rt][ct][r];
                if (do_elu) v = v > 0.f ? v + 1.f : __expf(v);
                kv_out[((size_t)b * 128 + row) * N_ + px] = bf16u(v);
            }
        }
    }
}

// ---------------------------------------------------------------------------
// K4 (MFMA): M += phik·v^T over pixels, Z += row-sums. (unchanged)
// ---------------------------------------------------------------------------
__global__ __launch_bounds__(256) void k_mz2(const unsigned short* __restrict__ kv,
                                             float* __restrict__ ws) {
    __shared__ __align__(16) unsigned short kv_s[128][136];   // 34816 B
    const int b = blockIdx.y, t = threadIdx.x, w = t >> 6, l = t & 63;
    const int zrow = t >> 2, zq = t & 3;
    f32x4 accm = (f32x4){0.f, 0.f, 0.f, 0.f};
    float z = 0.f;

    for (int st = 0; st < 8; ++st) {
        const int px0 = (blockIdx.x * 8 + st) * 128;
        __syncthreads();
        #pragma unroll
        for (int i = 0; i < 32; ++i) {
            const int e2 = t + 256 * i;                      // 8192 dwords
            const int row = e2 >> 6, pp = (e2 & 63) * 2;
            *(unsigned int*)&kv_s[row][pp] =
                *(const unsigned int*)&kv[((size_t)b * 128 + row) * N_ + px0 + pp];
        }
        __syncthreads();
        #pragma unroll
        for (int kc = 0; kc < 4; ++kc) {
            const short8b af = *(const short8b*)((const char*)&kv_s[w * 16 + (l & 15)][0]
                                                 + kc * 64 + (l >> 4) * 16);
            const short8b bf = *(const short8b*)((const char*)&kv_s[64 + w * 16 + (l & 15)][0]
                                                 + kc * 64 + (l >> 4) * 16);
            accm = __builtin_amdgcn_mfma_f32_16x16x32_bf16(af, bf, accm, 0, 0, 0);
        }
        #pragma unroll
        for (int j = 0; j < 16; ++j) {
            const unsigned int u = *(const unsigned int*)&kv_s[zrow][zq * 32 + j * 2];
            z += ubf((unsigned short)u) + ubf((unsigned short)(u >> 16));
        }
    }
    #pragma unroll
    for (int r = 0; r < 4; ++r) {
        const int d = (l >> 4) * 4 + r, e = l & 15;
        atomicAdd(&ws[OFF_M + b * 1024 + w * 256 + d * 16 + e], accm[r]);
    }
    atomicAdd(&ws[OFF_Z + b * 64 + zrow], z);
}

// ---------------------------------------------------------------------------
// K5 (MFMA): phi_q GEMM (K=256, double-buffered x staging, Wq frags in regs)
// -> in-wave den + psi (XOR-swizzled LDS) -> W2=Wo·M^T in-kernel (LDS aliased
// over the x staging buffers) -> W2·psi GEMM with per-rt fused epilogue.
// LDS 50176 B -> 3 blocks/CU; __launch_bounds__(256,3) caps VGPR at 170.
// ---------------------------------------------------------------------------
__global__ __launch_bounds__(256, 3) void k_out4(const float* __restrict__ x,
        const float* __restrict__ Wo, const float* __restrict__ bo,
        const float* __restrict__ ws, float* __restrict__ out) {
    __shared__ __align__(16) char lds[50176];
    char*  pq_s = lds;                      // [128][128B] XOR-swz psi; first 4KB = m_s
    char*  breg = lds + 16384;              // 32KB: x_s dbuf (2x10240) then w2_s alias
    float* bo_s = (float*)(lds + 49152);    // [256]

    const int b = blockIdx.y, px0 = blockIdx.x * 128;
    const int t = threadIdx.x, w = t >> 6, l = t & 63;
    const float* __restrict__ sv = ws + OFF_S + b * C_;
    const float* __restrict__ tv = ws + OFF_T + b * C_;
    const unsigned short* __restrict__ wkvq16 = (const unsigned short*)(ws + OFF_WKVQ);
    const float* __restrict__ xb = x + (size_t)b * C_ * N_ + px0;

    bo_s[t] = bo[t];
    float* m_s = (float*)pq_s;              // 4KB scratch, read only in W2 phase
    for (int i = t; i < 1024; i += 256) m_s[i] = ws[OFF_M + b * 1024 + i];
    float zr[4];
    #pragma unroll
    for (int r = 0; r < 4; ++r)
        zr[r] = ws[OFF_Z + b * 64 + w * 16 + (l >> 4) * 4 + r];

    // Wq fragments for all 8 K-steps -> registers (row = 128 + w*16 + (l&15))
    short8b afq[8];
    {
        const unsigned short* wq = wkvq16
            + (size_t)(128 + w * 16 + (l & 15)) * 256 + (l >> 4) * 8;
        #pragma unroll
        for (int ks = 0; ks < 8; ++ks) afq[ks] = *(const short8b*)(wq + ks * 32);
    }

    const int px_ = t & 127, half = t >> 7;
    char* xs0 = breg;
    char* xs1 = breg + 10240;

    f32x4 accq[8];
    #pragma unroll
    for (int j = 0; j < 8; ++j) accq[j] = (f32x4){0.f, 0.f, 0.f, 0.f};

    // ---- phase 1: phi_q GEMM with double-buffered, prefetched x staging ----
    {   // prologue: stage ks=0 into xs0
        float xf[16];
        #pragma unroll
        for (int i = 0; i < 16; ++i)
            xf[i] = xb[(size_t)(half * 16 + i) * N_ + px_];
        #pragma unroll
        for (int i = 0; i < 8; ++i) {
            const int c = half * 16 + 2 * i;
            const float a0 = fmaf(xf[2 * i],     sv[c],     tv[c]);
            const float a1 = fmaf(xf[2 * i + 1], sv[c + 1], tv[c + 1]);
            *(unsigned int*)(xs0 + px_ * 80 + (half * 16 + 2 * i) * 2) =
                ((unsigned int)bf16u(a1) << 16) | bf16u(a0);
        }
    }
    __syncthreads();
    #pragma unroll
    for (int ks = 0; ks < 8; ++ks) {
        char* xcur = (ks & 1) ? xs1 : xs0;
        char* xnxt = (ks & 1) ? xs0 : xs1;
        float xg[16];
        if (ks < 7) {                        // issue next-tile loads EARLY
            #pragma unroll
            for (int i = 0; i < 16; ++i)
                xg[i] = xb[(size_t)((ks + 1) * 32 + half * 16 + i) * N_ + px_];
        }
        #pragma unroll
        for (int ct = 0; ct < 8; ++ct) {     // MFMA on current buffer
            const short8b bfr = *(const short8b*)(xcur + (ct * 16 + (l & 15)) * 80
                                                  + (l >> 4) * 16);
            accq[ct] = __builtin_amdgcn_mfma_f32_16x16x32_bf16(
                           afq[ks], bfr, accq[ct], 0, 0, 0);
        }
        if (ks < 7) {                        // fold + write next buffer LATE
            #pragma unroll
            for (int i = 0; i < 8; ++i) {
                const int c = (ks + 1) * 32 + half * 16 + 2 * i;
                const float a0 = fmaf(xg[2 * i],     sv[c],     tv[c]);
                const float a1 = fmaf(xg[2 * i + 1], sv[c + 1], tv[c + 1]);
                *(unsigned int*)(xnxt + px_ * 80 + (half * 16 + 2 * i) * 2) =
                    ((unsigned int)bf16u(a1) << 16) | bf16u(a0);
            }
        }
        __syncthreads();
    }

    // ---- W2 = Wo·M^T -> w2_s (aliases x staging; phase 1 fully drained) ----
    char* w2_s = breg;                       // [256][128B] XOR-swizzled
    #pragma unroll
    for (int h = 0; h < NH_; ++h) {
        float wrow[16];
        #pragma unroll
        for (int j = 0; j < 4; ++j)
            *(float4*)&wrow[j * 4] = *(const float4*)&Wo[t * 64 + h * 16 + j * 4];
        float av[16];
        #pragma unroll
        for (int d = 0; d < 16; ++d) {
            float a = 0.f;
            #pragma unroll
            for (int e = 0; e < 16; ++e)
                a = fmaf(wrow[e], m_s[h * 256 + d * 16 + e], a);
            av[d] = a;
        }
        #pragma unroll
        for (int j = 0; j < 8; ++j) {
            const unsigned int pk = (unsigned int)bf16u(av[2 * j])
                                  | ((unsigned int)bf16u(av[2 * j + 1]) << 16);
            *(unsigned int*)(w2_s + t * 128 + ((h * 32 + j * 4) ^ ((t & 7) << 4))) = pk;
        }
    }
    __syncthreads();   // m_s reads done before psi overwrites pq_s

    // ---- phi, per-pixel den (in-wave shuffle), psi -> pq_s (swizzled) ----
    #pragma unroll
    for (int ct = 0; ct < 8; ++ct) {
        float p[4];
        #pragma unroll
        for (int r = 0; r < 4; ++r) {
            const float v = accq[ct][r];
            p[r] = v > 0.f ? v + 1.f : __expf(v);
        }
        float dp = 0.f;
        #pragma unroll
        for (int r = 0; r < 4; ++r) dp = fmaf(zr[r], p[r], dp);
        dp += __shfl_xor(dp, 16);
        dp += __shfl_xor(dp, 32);
        const float rd = 1.f / fmaxf(dp, 1e-4f);
        const int px = ct * 16 + (l & 15);
        const unsigned int lo = (unsigned int)bf16u(p[0] * rd)
                              | ((unsigned int)bf16u(p[1] * rd) << 16);
        const unsigned int hi = (unsigned int)bf16u(p[2] * rd)
                              | ((unsigned int)bf16u(p[3] * rd) << 16);
        const int off = (w * 32 + (l >> 4) * 8) ^ ((px & 7) << 4);
        *(unsigned long long*)(pq_s + px * 128 + off) =
            (unsigned long long)lo | ((unsigned long long)hi << 32);
    }
    __syncthreads();   // psi + W2 visible to all waves

    // ---- phase 3: out = W2 · psi (K=64), per-rt accumulate + fused epilogue ----
    short8b bfr[2][8];
    #pragma unroll
    for (int ksi = 0; ksi < 2; ++ksi)
        #pragma unroll
        for (int ct = 0; ct < 8; ++ct) {
            const int px = ct * 16 + (l & 15);
            bfr[ksi][ct] = *(const short8b*)(pq_s + px * 128
                             + ((ksi * 64 + (l >> 4) * 16) ^ ((px & 7) << 4)));
        }
    const float gate = ws[OFF_GATE + b];
    const float* __restrict__ xr = x + (size_t)b * C_ * N_;
    float* __restrict__ ob = out + (size_t)b * C_ * N_;
    #pragma unroll
    for (int rt = 0; rt < 4; ++rt) {
        f32x4 acc[8];
        #pragma unroll
        for (int j = 0; j < 8; ++j) acc[j] = (f32x4){0.f, 0.f, 0.f, 0.f};
        const int row = w * 64 + rt * 16 + (l & 15);
        #pragma unroll
        for (int ksi = 0; ksi < 2; ++ksi) {
            const short8b af = *(const short8b*)(w2_s + row * 128
                                 + ((ksi * 64 + (l >> 4) * 16) ^ ((row & 7) << 4)));
            #pragma unroll
            for (int ct = 0; ct < 8; ++ct)
                acc[ct] = __builtin_amdgcn_mfma_f32_16x16x32_bf16(
                              af, bfr[ksi][ct], acc[ct], 0, 0, 0);
        }
        #pragma unroll
        for (int ct = 0; ct < 8; ++ct) {
            const int px = px0 + ct * 16 + (l & 15);
            #pragma unroll
            for (int r = 0; r < 4; ++r) {
                const int orow = w * 64 + rt * 16 + (l >> 4) * 4 + r;
                const size_t off = (size_t)orow * N_ + px;
                ob[off] = fmaf(gate, acc[ct][r] + bo_s[orow], xr[off]);
            }
        }
    }
}

// ---------------------------------------------------------------------------
extern "C" void kernel_launch(void* const* d_in, const int* in_sizes, int n_in,
                              void* d_out, int out_size, void* d_ws, size_t ws_size,
                              hipStream_t stream) {
    const float* x   = (const float*)d_in[0];
    const float* gnw = (const float*)d_in[1];
    const float* gnb = (const float*)d_in[2];
    const float* Wk  = (const float*)d_in[3];
    const float* Wv  = (const float*)d_in[4];
    const float* Wq  = (const float*)d_in[5];
    const float* Wo  = (const float*)d_in[6];
    const float* bo  = (const float*)d_in[7];
    const float* M0  = (const float*)d_in[8];
    const float* Z0  = (const float*)d_in[9];
    const float* g1w = (const float*)d_in[10];
    const float* g1b = (const float*)d_in[11];
    const float* g2w = (const float*)d_in[12];
    const float* g2b = (const float*)d_in[13];
    float* out = (float*)d_out;
    float* ws  = (float*)d_ws;
    // K|V bf16 overlay in d_out bytes [0, 64MB): written by k_proj, read by
    // k_mz2, fully overwritten by k_out4 — stream-ordered, rewritten per call.
    unsigned short* kv_overlay = (unsigned short*)d_out;

    hipLaunchKernelGGL(k_stats, dim3(B_ * C_), dim3(256), 0, stream, x, ws);
    hipLaunchKernelGGL(k_cvtw,  dim3(192),     dim3(256), 0, stream, Wk, Wv, Wq, ws);
    hipLaunchKernelGGL(k_prep,  dim3(B_),      dim3(256), 0, stream,
                       gnw, gnb, M0, Z0, g1w, g1b, g2w, g2b, ws,
                       out + (size_t)B_ * C_ * N_);
    hipLaunchKernelGGL(k_proj,  dim3(N_ / 128, B_), dim3(256), 0, stream,
                       x, ws, kv_overlay);
    hipLaunchKernelGGL(k_mz2,   dim3(16, B_),  dim3(256), 0, stream, kv_overlay, ws);
    hipLaunchKernelGGL(k_out4,  dim3(N_ / 128, B_), dim3(256), 0, stream,
                       x, Wo, bo, ws, out);
}

// Round 7
// 349.449 us; speedup vs baseline: 8.1468x; 1.1534x over previous
//
#include <hip/hip_runtime.h>
#include <math.h>

typedef __attribute__((ext_vector_type(8))) short short8b;   // 8 bf16 = 4 VGPR
typedef __attribute__((ext_vector_type(4))) float f32x4;

#define B_   16
#define C_   256
#define N_   16384      // H*W
#define NH_  4
#define G_   8
#define CPG_ 32

// Workspace layout (float offsets) — total ~196 KB (proven-safe < 332 KB)
#define OFF_S    0        // [B][C] folded GN scale   (k_stats writes SUM here first)
#define OFF_T    4096     // [B][C] folded GN shift   (k_stats writes SQ here first)
#define OFF_SUM  OFF_S
#define OFF_SQ   OFF_T
#define OFF_M    8192     // [B][4][16][16] f32
#define OFF_Z    24576    // [B][64] f32
#define OFF_GATE 25600    // [B]
#define OFF_WKVQ 25616    // bf16 [192][256] (24576 floats)

static __device__ inline unsigned short bf16u(float f) {
    unsigned int u = __float_as_uint(f);
    return (unsigned short)((u + 0x7FFFu + ((u >> 16) & 1u)) >> 16);   // RNE
}
static __device__ inline float ubf(unsigned short u) {
    return __uint_as_float(((unsigned int)u) << 16);
}

// ---------------------------------------------------------------------------
// K1: per-(b,c) sum and sumsq over pixels. One block per (b,c).
// ---------------------------------------------------------------------------
__global__ __launch_bounds__(256) void k_stats(const float* __restrict__ x,
                                               float* __restrict__ ws) {
    const int bc = blockIdx.x;
    const float4* p4 = (const float4*)(x + (size_t)bc * N_);
    float s = 0.f, q = 0.f;
    #pragma unroll 4
    for (int i = threadIdx.x; i < N_ / 4; i += 256) {
        float4 v = p4[i];
        s += v.x + v.y + v.z + v.w;
        q += v.x * v.x + v.y * v.y + v.z * v.z + v.w * v.w;
    }
    #pragma unroll
    for (int o = 32; o > 0; o >>= 1) {
        s += __shfl_down(s, o);
        q += __shfl_down(q, o);
    }
    __shared__ float ls[4], lq[4];
    const int wid = threadIdx.x >> 6, lane = threadIdx.x & 63;
    if (lane == 0) { ls[wid] = s; lq[wid] = q; }
    __syncthreads();
    if (threadIdx.x == 0) {
        ws[OFF_SUM + bc] = ls[0] + ls[1] + ls[2] + ls[3];
        ws[OFF_SQ  + bc] = lq[0] + lq[1] + lq[2] + lq[3];
    }
}

// ---------------------------------------------------------------------------
// K_cvtw: Wk|Wv|Wq -> bf16 table [192][256], row-major (K contiguous).
// ---------------------------------------------------------------------------
__global__ __launch_bounds__(256) void k_cvtw(const float* __restrict__ Wk,
        const float* __restrict__ Wv, const float* __restrict__ Wq,
        float* __restrict__ ws) {
    unsigned short* wkvq = (unsigned short*)(ws + OFF_WKVQ);
    const int r = blockIdx.x, t = threadIdx.x;
    const float* src = r < 64 ? Wk + r * C_
                     : r < 128 ? Wv + (r - 64) * C_
                     : Wq + (r - 128) * C_;
    wkvq[r * 256 + t] = bf16u(src[t]);
}

// ---------------------------------------------------------------------------
// K2: per-batch prep — GN fold (in-place over SUM/SQ), gate MLP, M/Z init.
// ---------------------------------------------------------------------------
__global__ __launch_bounds__(256) void k_prep(
        const float* __restrict__ gnw, const float* __restrict__ gnb,
        const float* __restrict__ M0,  const float* __restrict__ Z0,
        const float* __restrict__ g1w, const float* __restrict__ g1b,
        const float* __restrict__ g2w, const float* __restrict__ g2b,
        float* __restrict__ ws, float* __restrict__ out_gate) {
    const int b = blockIdx.x, t = threadIdx.x;
    __shared__ float mu[G_], rs[G_];
    __shared__ float pooled[C_];
    __shared__ float hidden[64];

    if (t < G_) {
        float S = 0.f, Q = 0.f;
        for (int c = t * CPG_; c < (t + 1) * CPG_; ++c) {
            S += ws[OFF_SUM + b * C_ + c];
            Q += ws[OFF_SQ  + b * C_ + c];
        }
        const float cnt = (float)(CPG_ * N_);
        const float m = S / cnt;
        const float var = Q / cnt - m * m;
        mu[t] = m;
        rs[t] = rsqrtf(var + 1e-5f);
    }
    __syncthreads();
    {
        const int c = t;
        const int g = c / CPG_;
        const float sumc = ws[OFF_SUM + b * C_ + c];   // read BEFORE in-place overwrite
        const float sc = rs[g] * gnw[c];
        const float tc = gnb[c] - mu[g] * sc;
        ws[OFF_S + b * C_ + c] = sc;
        ws[OFF_T + b * C_ + c] = tc;
        pooled[c] = fmaf(sumc * (1.f / (float)N_), sc, tc);
    }
    __syncthreads();
    if (t < 64) {
        float a = g1b[t];
        for (int c = 0; c < C_; ++c) a = fmaf(pooled[c], g1w[t * C_ + c], a);
        hidden[t] = 0.5f * a * (1.f + erff(a * 0.70710678118654752f));
    }
    __syncthreads();
    if (t == 0) {
        float z = g2b[0];
        for (int j = 0; j < 64; ++j) z = fmaf(hidden[j], g2w[j], z);
        const float gate = 1.f / (1.f + expf(-z));
        ws[OFF_GATE + b] = gate;
        out_gate[b] = gate;
    }
    for (int i = t; i < NH_ * 256; i += 256) ws[OFF_M + b * 1024 + i] = M0[i];
    for (int i = t; i < 64;        i += 256) ws[OFF_Z + b * 64 + i]   = Z0[i];
}

// ---------------------------------------------------------------------------
// K3 (MFMA, fused): K|V projection GEMM ([128 rows][128 px], K=256) then
// in-block M += phik·v^T (per-head MFMA over the 128-px tile) and Z row-sums
// with LDS pre-reduction. phik/v never leave the block — removes the 64MB
// kv write + 64MB read and the separate k_mz2 dispatch.
// LDS: phase A staging (w_s|x_s, 20KB) is aliased by the phase-B kvt tile
// (34.8KB, same layout/frag access as the proven k_mz2) — barrier-separated.
// ---------------------------------------------------------------------------
__global__ __launch_bounds__(256) void k_projmz(const float* __restrict__ x,
                                                float* __restrict__ ws) {
    __shared__ __align__(16) char lds[35072];
    char* w_s = lds;                          // [128][80B]  phase A
    char* x_s = lds + 10240;                  // [128][80B]  phase A
    unsigned short (*kvt)[136] = (unsigned short (*)[136])lds;   // phase B/C, aliases A
    float* z_red = (float*)(lds + 34816);     // [64], outside the aliased region

    const int b = blockIdx.y, px0 = blockIdx.x * 128;
    const int t = threadIdx.x, w = t >> 6, l = t & 63;
    const float* __restrict__ sv = ws + OFF_S + b * C_;
    const float* __restrict__ tv = ws + OFF_T + b * C_;
    const unsigned int* __restrict__ wkvq32 = (const unsigned int*)(ws + OFF_WKVQ);
    const float* __restrict__ xb = x + (size_t)b * C_ * N_ + px0;

    if (t < 64) z_red[t] = 0.f;

    f32x4 acc[2][8];
    #pragma unroll
    for (int i = 0; i < 2; ++i)
        #pragma unroll
        for (int j = 0; j < 8; ++j) acc[i][j] = (f32x4){0.f, 0.f, 0.f, 0.f};

    // ---- phase A: projection GEMM (unchanged from proven k_proj) ----
    for (int ks = 0; ks < 8; ++ks) {
        __syncthreads();
        #pragma unroll
        for (int i = 0; i < 8; ++i) {
            const int e2 = t + 256 * i;
            const int row = e2 >> 4, kp = e2 & 15;
            *(unsigned int*)(w_s + row * 80 + kp * 4) =
                wkvq32[row * 128 + ks * 16 + kp];
        }
        {
            const int px = t & 127, half = t >> 7;
            #pragma unroll
            for (int i = 0; i < 8; ++i) {
                const int lc = half * 16 + i * 2;
                const int c = ks * 32 + lc;
                const float a0 = fmaf(xb[(size_t)c * N_ + px],       sv[c],     tv[c]);
                const float a1 = fmaf(xb[(size_t)(c + 1) * N_ + px], sv[c + 1], tv[c + 1]);
                *(unsigned int*)(x_s + px * 80 + lc * 2) =
                    ((unsigned int)bf16u(a1) << 16) | bf16u(a0);
            }
        }
        __syncthreads();
        short8b bfr[8];
        #pragma unroll
        for (int ct = 0; ct < 8; ++ct)
            bfr[ct] = *(const short8b*)(x_s + (ct * 16 + (l & 15)) * 80 + (l >> 4) * 16);
        #pragma unroll
        for (int rt = 0; rt < 2; ++rt) {
            const int row = w * 32 + rt * 16 + (l & 15);
            const short8b af = *(const short8b*)(w_s + row * 80 + (l >> 4) * 16);
            #pragma unroll
            for (int ct = 0; ct < 8; ++ct)
                acc[rt][ct] = __builtin_amdgcn_mfma_f32_16x16x32_bf16(
                                  af, bfr[ct], acc[rt][ct], 0, 0, 0);
        }
    }
    __syncthreads();   // staging buffers dead; safe to overwrite with kvt

    // ---- phase B: phik/v tiles -> LDS (elu+1 on phik rows 0..63) ----
    #pragma unroll
    for (int rt = 0; rt < 2; ++rt) {
        const int base = w * 32 + rt * 16;
        const bool do_elu = base < 64;
        #pragma unroll
        for (int ct = 0; ct < 8; ++ct) {
            const int px = ct * 16 + (l & 15);
            #pragma unroll
            for (int r = 0; r < 4; ++r) {
                const int row = base + (l >> 4) * 4 + r;
                float v = acc[rt][ct][r];
                if (do_elu) v = v > 0.f ? v + 1.f : __expf(v);
                kvt[row][px] = bf16u(v);
            }
        }
    }
    __syncthreads();

    // ---- phase C: per-head M MFMA + Z row-sums (k_mz2's proven patterns) ----
    f32x4 accm = (f32x4){0.f, 0.f, 0.f, 0.f};
    #pragma unroll
    for (int kc = 0; kc < 4; ++kc) {
        const short8b af = *(const short8b*)((const char*)&kvt[w * 16 + (l & 15)][0]
                                             + kc * 64 + (l >> 4) * 16);
        const short8b bf = *(const short8b*)((const char*)&kvt[64 + w * 16 + (l & 15)][0]
                                             + kc * 64 + (l >> 4) * 16);
        accm = __builtin_amdgcn_mfma_f32_16x16x32_bf16(af, bf, accm, 0, 0, 0);
    }
    {
        const int zrow = t >> 2, zq = t & 3;
        float z = 0.f;
        #pragma unroll
        for (int j = 0; j < 16; ++j) {
            const unsigned int u = *(const unsigned int*)&kvt[zrow][zq * 32 + j * 2];
            z += ubf((unsigned short)u) + ubf((unsigned short)(u >> 16));
        }
        atomicAdd(&z_red[zrow], z);
    }
    #pragma unroll
    for (int r = 0; r < 4; ++r) {
        const int d = (l >> 4) * 4 + r, e = l & 15;
        atomicAdd(&ws[OFF_M + b * 1024 + w * 256 + d * 16 + e], accm[r]);
    }
    __syncthreads();
    if (t < 64) atomicAdd(&ws[OFF_Z + b * 64 + t], z_red[t]);
}

// ---------------------------------------------------------------------------
// K4 (MFMA): phi_q GEMM (K=256, 3-deep pipelined x staging: loads issued 2
// tiles ahead into ping-pong regs, triple-buffered LDS) -> in-wave den + psi
// (XOR-swz LDS) -> W2=Wo·M^T in-kernel (aliases staging LDS) -> W2·psi GEMM
// with per-rt fused epilogue; nontemporal out stores (out never re-read).
// ---------------------------------------------------------------------------
__global__ __launch_bounds__(256, 3) void k_out4(const float* __restrict__ x,
        const float* __restrict__ Wo, const float* __restrict__ bo,
        const float* __restrict__ ws, float* __restrict__ out) {
    __shared__ __align__(16) char lds[50176];
    char*  pq_s = lds;                      // [128][128B] XOR-swz psi; first 4KB = m_s
    char*  breg = lds + 16384;              // 32KB: x_s 3-buf (3x10240) then w2_s alias
    float* bo_s = (float*)(lds + 49152);    // [256]

    const int b = blockIdx.y, px0 = blockIdx.x * 128;
    const int t = threadIdx.x, w = t >> 6, l = t & 63;
    const float* __restrict__ sv = ws + OFF_S + b * C_;
    const float* __restrict__ tv = ws + OFF_T + b * C_;
    const unsigned short* __restrict__ wkvq16 = (const unsigned short*)(ws + OFF_WKVQ);
    const float* __restrict__ xb = x + (size_t)b * C_ * N_ + px0;

    bo_s[t] = bo[t];
    float* m_s = (float*)pq_s;              // 4KB scratch, read only in W2 phase
    for (int i = t; i < 1024; i += 256) m_s[i] = ws[OFF_M + b * 1024 + i];
    float zr[4];
    #pragma unroll
    for (int r = 0; r < 4; ++r)
        zr[r] = ws[OFF_Z + b * 64 + w * 16 + (l >> 4) * 4 + r];

    // Wq fragments for all 8 K-steps -> registers
    short8b afq[8];
    {
        const unsigned short* wq = wkvq16
            + (size_t)(128 + w * 16 + (l & 15)) * 256 + (l >> 4) * 8;
        #pragma unroll
        for (int ks = 0; ks < 8; ++ks) afq[ks] = *(const short8b*)(wq + ks * 32);
    }

    const int px_ = t & 127, half = t >> 7;
    char* xs0 = breg;
    char* xs1 = breg + 10240;
    char* xs2 = breg + 20480;

    f32x4 accq[8];
    #pragma unroll
    for (int j = 0; j < 8; ++j) accq[j] = (f32x4){0.f, 0.f, 0.f, 0.f};

    // ---- phase 1: phi_q GEMM, 3-deep pipeline (loads 2 tiles ahead) ----
    float xg[2][16];
    {   // prologue: tile 0 -> regs -> xs0; tile 1 -> regs (held)
        #pragma unroll
        for (int i = 0; i < 16; ++i)
            xg[0][i] = xb[(size_t)(half * 16 + i) * N_ + px_];
        #pragma unroll
        for (int i = 0; i < 8; ++i) {
            const int c = half * 16 + 2 * i;
            const float a0 = fmaf(xg[0][2 * i],     sv[c],     tv[c]);
            const float a1 = fmaf(xg[0][2 * i + 1], sv[c + 1], tv[c + 1]);
            *(unsigned int*)(xs0 + px_ * 80 + (half * 16 + 2 * i) * 2) =
                ((unsigned int)bf16u(a1) << 16) | bf16u(a0);
        }
        #pragma unroll
        for (int i = 0; i < 16; ++i)
            xg[1][i] = xb[(size_t)(32 + half * 16 + i) * N_ + px_];
    }
    __syncthreads();
    #pragma unroll
    for (int ks = 0; ks < 8; ++ks) {
        char* xcur = (ks % 3 == 0) ? xs0 : (ks % 3 == 1) ? xs1 : xs2;
        if (ks + 2 < 8) {                    // issue loads 2 tiles ahead
            #pragma unroll
            for (int i = 0; i < 16; ++i)
                xg[ks & 1][i] = xb[(size_t)((ks + 2) * 32 + half * 16 + i) * N_ + px_];
        }
        #pragma unroll
        for (int ct = 0; ct < 8; ++ct) {     // MFMA on current buffer
            const short8b bfr = *(const short8b*)(xcur + (ct * 16 + (l & 15)) * 80
                                                  + (l >> 4) * 16);
            accq[ct] = __builtin_amdgcn_mfma_f32_16x16x32_bf16(
                           afq[ks], bfr, accq[ct], 0, 0, 0);
        }
        if (ks + 1 < 8) {                    // fold + write tile ks+1 LATE
            char* xnxt = ((ks + 1) % 3 == 0) ? xs0 : ((ks + 1) % 3 == 1) ? xs1 : xs2;
            #pragma unroll
            for (int i = 0; i < 8; ++i) {
                const int c = (ks + 1) * 32 + half * 16 + 2 * i;
                const float a0 = fmaf(xg[(ks + 1) & 1][2 * i],     sv[c],     tv[c]);
                const float a1 = fmaf(xg[(ks + 1) & 1][2 * i + 1], sv[c + 1], tv[c + 1]);
                *(unsigned int*)(xnxt + px_ * 80 + (half * 16 + 2 * i) * 2) =
                    ((unsigned int)bf16u(a1) << 16) | bf16u(a0);
            }
        }
        __syncthreads();
    }

    // ---- W2 = Wo·M^T -> w2_s (aliases x staging; phase 1 fully drained) ----
    char* w2_s = breg;                       // [256][128B] XOR-swizzled
    #pragma unroll
    for (int h = 0; h < NH_; ++h) {
        float wrow[16];
        #pragma unroll
        for (int j = 0; j < 4; ++j)
            *(float4*)&wrow[j * 4] = *(const float4*)&Wo[t * 64 + h * 16 + j * 4];
        float av[16];
        #pragma unroll
        for (int d = 0; d < 16; ++d) {
            float a = 0.f;
            #pragma unroll
            for (int e = 0; e < 16; ++e)
                a = fmaf(wrow[e], m_s[h * 256 + d * 16 + e], a);
            av[d] = a;
        }
        #pragma unroll
        for (int j = 0; j < 8; ++j) {
            const unsigned int pk = (unsigned int)bf16u(av[2 * j])
                                  | ((unsigned int)bf16u(av[2 * j + 1]) << 16);
            *(unsigned int*)(w2_s + t * 128 + ((h * 32 + j * 4) ^ ((t & 7) << 4))) = pk;
        }
    }
    __syncthreads();   // m_s reads done before psi overwrites pq_s

    // ---- phi, per-pixel den (in-wave shuffle), psi -> pq_s (swizzled) ----
    #pragma unroll
    for (int ct = 0; ct < 8; ++ct) {
        float p[4];
        #pragma unroll
        for (int r = 0; r < 4; ++r) {
            const float v = accq[ct][r];
            p[r] = v > 0.f ? v + 1.f : __expf(v);
        }
        float dp = 0.f;
        #pragma unroll
        for (int r = 0; r < 4; ++r) dp = fmaf(zr[r], p[r], dp);
        dp += __shfl_xor(dp, 16);
        dp += __shfl_xor(dp, 32);
        const float rd = 1.f / fmaxf(dp, 1e-4f);
        const int px = ct * 16 + (l & 15);
        const unsigned int lo = (unsigned int)bf16u(p[0] * rd)
                              | ((unsigned int)bf16u(p[1] * rd) << 16);
        const unsigned int hi = (unsigned int)bf16u(p[2] * rd)
                              | ((unsigned int)bf16u(p[3] * rd) << 16);
        const int off = (w * 32 + (l >> 4) * 8) ^ ((px & 7) << 4);
        *(unsigned long long*)(pq_s + px * 128 + off) =
            (unsigned long long)lo | ((unsigned long long)hi << 32);
    }
    __syncthreads();   // psi + W2 visible to all waves

    // ---- phase 3: out = W2 · psi (K=64), per-rt accumulate + fused epilogue ----
    short8b bfr[2][8];
    #pragma unroll
    for (int ksi = 0; ksi < 2; ++ksi)
        #pragma unroll
        for (int ct = 0; ct < 8; ++ct) {
            const int px = ct * 16 + (l & 15);
            bfr[ksi][ct] = *(const short8b*)(pq_s + px * 128
                             + ((ksi * 64 + (l >> 4) * 16) ^ ((px & 7) << 4)));
        }
    const float gate = ws[OFF_GATE + b];
    const float* __restrict__ xr = x + (size_t)b * C_ * N_;
    float* __restrict__ ob = out + (size_t)b * C_ * N_;
    #pragma unroll
    for (int rt = 0; rt < 4; ++rt) {
        f32x4 acc[8];
        #pragma unroll
        for (int j = 0; j < 8; ++j) acc[j] = (f32x4){0.f, 0.f, 0.f, 0.f};
        const int row = w * 64 + rt * 16 + (l & 15);
        #pragma unroll
        for (int ksi = 0; ksi < 2; ++ksi) {
            const short8b af = *(const short8b*)(w2_s + row * 128
                                 + ((ksi * 64 + (l >> 4) * 16) ^ ((row & 7) << 4)));
            #pragma unroll
            for (int ct = 0; ct < 8; ++ct)
                acc[ct] = __builtin_amdgcn_mfma_f32_16x16x32_bf16(
                              af, bfr[ksi][ct], acc[ct], 0, 0, 0);
        }
        #pragma unroll
        for (int ct = 0; ct < 8; ++ct) {
            const int px = px0 + ct * 16 + (l & 15);
            #pragma unroll
            for (int r = 0; r < 4; ++r) {
                const int orow = w * 64 + rt * 16 + (l >> 4) * 4 + r;
                const size_t off = (size_t)orow * N_ + px;
                const float res = fmaf(gate, acc[ct][r] + bo_s[orow], xr[off]);
                __builtin_nontemporal_store(res, &ob[off]);
            }
        }
    }
}

// ---------------------------------------------------------------------------
extern "C" void kernel_launch(void* const* d_in, const int* in_sizes, int n_in,
                              void* d_out, int out_size, void* d_ws, size_t ws_size,
                              hipStream_t stream) {
    const float* x   = (const float*)d_in[0];
    const float* gnw = (const float*)d_in[1];
    const float* gnb = (const float*)d_in[2];
    const float* Wk  = (const float*)d_in[3];
    const float* Wv  = (const float*)d_in[4];
    const float* Wq  = (const float*)d_in[5];
    const float* Wo  = (const float*)d_in[6];
    const float* bo  = (const float*)d_in[7];
    const float* M0  = (const float*)d_in[8];
    const float* Z0  = (const float*)d_in[9];
    const float* g1w = (const float*)d_in[10];
    const float* g1b = (const float*)d_in[11];
    const float* g2w = (const float*)d_in[12];
    const float* g2b = (const float*)d_in[13];
    float* out = (float*)d_out;
    float* ws  = (float*)d_ws;

    hipLaunchKernelGGL(k_stats,  dim3(B_ * C_), dim3(256), 0, stream, x, ws);
    hipLaunchKernelGGL(k_cvtw,   dim3(192),     dim3(256), 0, stream, Wk, Wv, Wq, ws);
    hipLaunchKernelGGL(k_prep,   dim3(B_),      dim3(256), 0, stream,
                       gnw, gnb, M0, Z0, g1w, g1b, g2w, g2b, ws,
                       out + (size_t)B_ * C_ * N_);
    hipLaunchKernelGGL(k_projmz, dim3(N_ / 128, B_), dim3(256), 0, stream, x, ws);
    hipLaunchKernelGGL(k_out4,   dim3(N_ / 128, B_), dim3(256), 0, stream,
                       x, Wo, bo, ws, out);
}

// Round 8
// 301.985 us; speedup vs baseline: 9.4272x; 1.1572x over previous
//
#include <hip/hip_runtime.h>
#include <math.h>

typedef __attribute__((ext_vector_type(8))) short short8b;   // 8 bf16 = 4 VGPR
typedef __attribute__((ext_vector_type(4))) float f32x4;

#define B_   16
#define C_   256
#define N_   16384      // H*W
#define NH_  4
#define G_   8
#define CPG_ 32

// Workspace layout (float offsets) — total ~196 KB (proven-safe < 332 KB)
#define OFF_S    0        // [B][C] folded GN scale   (k_stats writes SUM here first)
#define OFF_T    4096     // [B][C] folded GN shift   (k_stats writes SQ here first)
#define OFF_SUM  OFF_S
#define OFF_SQ   OFF_T
#define OFF_M    8192     // [B][4][16][16] f32
#define OFF_Z    24576    // [B][64] f32
#define OFF_GATE 25600    // [B]
#define OFF_WKVQ 25616    // bf16 [192][256] (24576 floats)

static __device__ inline unsigned short bf16u(float f) {
    unsigned int u = __float_as_uint(f);
    return (unsigned short)((u + 0x7FFFu + ((u >> 16) & 1u)) >> 16);   // RNE
}
static __device__ inline float ubf(unsigned short u) {
    return __uint_as_float(((unsigned int)u) << 16);
}

// ---------------------------------------------------------------------------
// K1: per-(b,c) sum and sumsq over pixels. One block per (b,c).
// ---------------------------------------------------------------------------
__global__ __launch_bounds__(256) void k_stats(const float* __restrict__ x,
                                               float* __restrict__ ws) {
    const int bc = blockIdx.x;
    const float4* p4 = (const float4*)(x + (size_t)bc * N_);
    float s = 0.f, q = 0.f;
    #pragma unroll 4
    for (int i = threadIdx.x; i < N_ / 4; i += 256) {
        float4 v = p4[i];
        s += v.x + v.y + v.z + v.w;
        q += v.x * v.x + v.y * v.y + v.z * v.z + v.w * v.w;
    }
    #pragma unroll
    for (int o = 32; o > 0; o >>= 1) {
        s += __shfl_down(s, o);
        q += __shfl_down(q, o);
    }
    __shared__ float ls[4], lq[4];
    const int wid = threadIdx.x >> 6, lane = threadIdx.x & 63;
    if (lane == 0) { ls[wid] = s; lq[wid] = q; }
    __syncthreads();
    if (threadIdx.x == 0) {
        ws[OFF_SUM + bc] = ls[0] + ls[1] + ls[2] + ls[3];
        ws[OFF_SQ  + bc] = lq[0] + lq[1] + lq[2] + lq[3];
    }
}

// ---------------------------------------------------------------------------
// K_cvtw: Wk|Wv|Wq -> bf16 table [192][256], row-major (K contiguous).
// ---------------------------------------------------------------------------
__global__ __launch_bounds__(256) void k_cvtw(const float* __restrict__ Wk,
        const float* __restrict__ Wv, const float* __restrict__ Wq,
        float* __restrict__ ws) {
    unsigned short* wkvq = (unsigned short*)(ws + OFF_WKVQ);
    const int r = blockIdx.x, t = threadIdx.x;
    const float* src = r < 64 ? Wk + r * C_
                     : r < 128 ? Wv + (r - 64) * C_
                     : Wq + (r - 128) * C_;
    wkvq[r * 256 + t] = bf16u(src[t]);
}

// ---------------------------------------------------------------------------
// K2: per-batch prep — GN fold (in-place over SUM/SQ), gate MLP, M/Z init.
// ---------------------------------------------------------------------------
__global__ __launch_bounds__(256) void k_prep(
        const float* __restrict__ gnw, const float* __restrict__ gnb,
        const float* __restrict__ M0,  const float* __restrict__ Z0,
        const float* __restrict__ g1w, const float* __restrict__ g1b,
        const float* __restrict__ g2w, const float* __restrict__ g2b,
        float* __restrict__ ws, float* __restrict__ out_gate) {
    const int b = blockIdx.x, t = threadIdx.x;
    __shared__ float mu[G_], rs[G_];
    __shared__ float pooled[C_];
    __shared__ float hidden[64];

    if (t < G_) {
        float S = 0.f, Q = 0.f;
        for (int c = t * CPG_; c < (t + 1) * CPG_; ++c) {
            S += ws[OFF_SUM + b * C_ + c];
            Q += ws[OFF_SQ  + b * C_ + c];
        }
        const float cnt = (float)(CPG_ * N_);
        const float m = S / cnt;
        const float var = Q / cnt - m * m;
        mu[t] = m;
        rs[t] = rsqrtf(var + 1e-5f);
    }
    __syncthreads();
    {
        const int c = t;
        const int g = c / CPG_;
        const float sumc = ws[OFF_SUM + b * C_ + c];   // read BEFORE in-place overwrite
        const float sc = rs[g] * gnw[c];
        const float tc = gnb[c] - mu[g] * sc;
        ws[OFF_S + b * C_ + c] = sc;
        ws[OFF_T + b * C_ + c] = tc;
        pooled[c] = fmaf(sumc * (1.f / (float)N_), sc, tc);
    }
    __syncthreads();
    if (t < 64) {
        float a = g1b[t];
        for (int c = 0; c < C_; ++c) a = fmaf(pooled[c], g1w[t * C_ + c], a);
        hidden[t] = 0.5f * a * (1.f + erff(a * 0.70710678118654752f));
    }
    __syncthreads();
    if (t == 0) {
        float z = g2b[0];
        for (int j = 0; j < 64; ++j) z = fmaf(hidden[j], g2w[j], z);
        const float gate = 1.f / (1.f + expf(-z));
        ws[OFF_GATE + b] = gate;
        out_gate[b] = gate;
    }
    for (int i = t; i < NH_ * 256; i += 256) ws[OFF_M + b * 1024 + i] = M0[i];
    for (int i = t; i < 64;        i += 256) ws[OFF_Z + b * 64 + i]   = Z0[i];
}

// ---------------------------------------------------------------------------
// K3 (MFMA, fused): K|V projection GEMM ([128 rows][128 px], K=256) then
// in-block M += phik·v^T and Z row-sums. (unchanged from round 7 — proven)
// ---------------------------------------------------------------------------
__global__ __launch_bounds__(256) void k_projmz(const float* __restrict__ x,
                                                float* __restrict__ ws) {
    __shared__ __align__(16) char lds[35072];
    char* w_s = lds;                          // [128][80B]  phase A
    char* x_s = lds + 10240;                  // [128][80B]  phase A
    unsigned short (*kvt)[136] = (unsigned short (*)[136])lds;   // phase B/C, aliases A
    float* z_red = (float*)(lds + 34816);     // [64], outside the aliased region

    const int b = blockIdx.y, px0 = blockIdx.x * 128;
    const int t = threadIdx.x, w = t >> 6, l = t & 63;
    const float* __restrict__ sv = ws + OFF_S + b * C_;
    const float* __restrict__ tv = ws + OFF_T + b * C_;
    const unsigned int* __restrict__ wkvq32 = (const unsigned int*)(ws + OFF_WKVQ);
    const float* __restrict__ xb = x + (size_t)b * C_ * N_ + px0;

    if (t < 64) z_red[t] = 0.f;

    f32x4 acc[2][8];
    #pragma unroll
    for (int i = 0; i < 2; ++i)
        #pragma unroll
        for (int j = 0; j < 8; ++j) acc[i][j] = (f32x4){0.f, 0.f, 0.f, 0.f};

    for (int ks = 0; ks < 8; ++ks) {
        __syncthreads();
        #pragma unroll
        for (int i = 0; i < 8; ++i) {
            const int e2 = t + 256 * i;
            const int row = e2 >> 4, kp = e2 & 15;
            *(unsigned int*)(w_s + row * 80 + kp * 4) =
                wkvq32[row * 128 + ks * 16 + kp];
        }
        {
            const int px = t & 127, half = t >> 7;
            #pragma unroll
            for (int i = 0; i < 8; ++i) {
                const int lc = half * 16 + i * 2;
                const int c = ks * 32 + lc;
                const float a0 = fmaf(xb[(size_t)c * N_ + px],       sv[c],     tv[c]);
                const float a1 = fmaf(xb[(size_t)(c + 1) * N_ + px], sv[c + 1], tv[c + 1]);
                *(unsigned int*)(x_s + px * 80 + lc * 2) =
                    ((unsigned int)bf16u(a1) << 16) | bf16u(a0);
            }
        }
        __syncthreads();
        short8b bfr[8];
        #pragma unroll
        for (int ct = 0; ct < 8; ++ct)
            bfr[ct] = *(const short8b*)(x_s + (ct * 16 + (l & 15)) * 80 + (l >> 4) * 16);
        #pragma unroll
        for (int rt = 0; rt < 2; ++rt) {
            const int row = w * 32 + rt * 16 + (l & 15);
            const short8b af = *(const short8b*)(w_s + row * 80 + (l >> 4) * 16);
            #pragma unroll
            for (int ct = 0; ct < 8; ++ct)
                acc[rt][ct] = __builtin_amdgcn_mfma_f32_16x16x32_bf16(
                                  af, bfr[ct], acc[rt][ct], 0, 0, 0);
        }
    }
    __syncthreads();   // staging buffers dead; safe to overwrite with kvt

    #pragma unroll
    for (int rt = 0; rt < 2; ++rt) {
        const int base = w * 32 + rt * 16;
        const bool do_elu = base < 64;
        #pragma unroll
        for (int ct = 0; ct < 8; ++ct) {
            const int px = ct * 16 + (l & 15);
            #pragma unroll
            for (int r = 0; r < 4; ++r) {
                const int row = base + (l >> 4) * 4 + r;
                float v = acc[rt][ct][r];
                if (do_elu) v = v > 0.f ? v + 1.f : __expf(v);
                kvt[row][px] = bf16u(v);
            }
        }
    }
    __syncthreads();

    f32x4 accm = (f32x4){0.f, 0.f, 0.f, 0.f};
    #pragma unroll
    for (int kc = 0; kc < 4; ++kc) {
        const short8b af = *(const short8b*)((const char*)&kvt[w * 16 + (l & 15)][0]
                                             + kc * 64 + (l >> 4) * 16);
        const short8b bf = *(const short8b*)((const char*)&kvt[64 + w * 16 + (l & 15)][0]
                                             + kc * 64 + (l >> 4) * 16);
        accm = __builtin_amdgcn_mfma_f32_16x16x32_bf16(af, bf, accm, 0, 0, 0);
    }
    {
        const int zrow = t >> 2, zq = t & 3;
        float z = 0.f;
        #pragma unroll
        for (int j = 0; j < 16; ++j) {
            const unsigned int u = *(const unsigned int*)&kvt[zrow][zq * 32 + j * 2];
            z += ubf((unsigned short)u) + ubf((unsigned short)(u >> 16));
        }
        atomicAdd(&z_red[zrow], z);
    }
    #pragma unroll
    for (int r = 0; r < 4; ++r) {
        const int d = (l >> 4) * 4 + r, e = l & 15;
        atomicAdd(&ws[OFF_M + b * 1024 + w * 256 + d * 16 + e], accm[r]);
    }
    __syncthreads();
    if (t < 64) atomicAdd(&ws[OFF_Z + b * 64 + t], z_red[t]);
}

// ---------------------------------------------------------------------------
// K4 (MFMA): 256-px tile, 512 threads (8 waves), ~75KB LDS -> 2 blocks/CU
// (16 waves/CU). Phase 1: phi_q GEMM (K=256, double-buffered reg-prefetch
// staging); wave w -> head w>>1, px-half w&1. Then in-wave den + psi (XOR-swz)
// -> W2=Wo·M^T (2 heads/thread across 512 thr, aliases staging LDS) ->
// W2·psi GEMM (B-frags streamed from LDS to keep VGPR<=128) + fused epilogue.
// ---------------------------------------------------------------------------
__global__ __launch_bounds__(512, 4) void k_out5(const float* __restrict__ x,
        const float* __restrict__ Wo, const float* __restrict__ bo,
        const float* __restrict__ ws, float* __restrict__ out) {
    __shared__ __align__(16) char lds[74752];
    char*  pq_s = lds;                      // [256][128B] XOR-swz psi; first 4KB = m_s
    char*  breg = lds + 32768;              // 40KB: xs dbuf (2x20480); w2_s alias
    float* bo_s = (float*)(lds + 73728);    // [256]

    const int b = blockIdx.y, px0 = blockIdx.x * 256;
    const int t = threadIdx.x, w = t >> 6, l = t & 63;
    const int h = w >> 1;                   // head
    const int pxw = (w & 1) * 128;          // px half owned in MFMA phases
    const float* __restrict__ sv = ws + OFF_S + b * C_;
    const float* __restrict__ tv = ws + OFF_T + b * C_;
    const unsigned short* __restrict__ wkvq16 = (const unsigned short*)(ws + OFF_WKVQ);
    const float* __restrict__ xb = x + (size_t)b * C_ * N_ + px0;

    if (t < 256) bo_s[t] = bo[t];
    float* m_s = (float*)pq_s;              // 4KB scratch, read only in W2 phase
    for (int i = t; i < 1024; i += 512) m_s[i] = ws[OFF_M + b * 1024 + i];
    float zr[4];
    #pragma unroll
    for (int r = 0; r < 4; ++r)
        zr[r] = ws[OFF_Z + b * 64 + h * 16 + (l >> 4) * 4 + r];

    // Wq fragments for all 8 K-steps -> registers (row = 128 + h*16 + (l&15))
    short8b afq[8];
    {
        const unsigned short* wq = wkvq16
            + (size_t)(128 + h * 16 + (l & 15)) * 256 + (l >> 4) * 8;
        #pragma unroll
        for (int ks = 0; ks < 8; ++ks) afq[ks] = *(const short8b*)(wq + ks * 32);
    }

    const int px_ = t & 255, half = t >> 8;
    char* xs0 = breg;
    char* xs1 = breg + 20480;

    f32x4 accq[8];
    #pragma unroll
    for (int j = 0; j < 8; ++j) accq[j] = (f32x4){0.f, 0.f, 0.f, 0.f};

    // ---- phase 1: phi_q GEMM, double-buffered with early reg prefetch ----
    {   // prologue: stage ks=0 into xs0
        float xf[16];
        #pragma unroll
        for (int i = 0; i < 16; ++i)
            xf[i] = xb[(size_t)(half * 16 + i) * N_ + px_];
        #pragma unroll
        for (int i = 0; i < 8; ++i) {
            const int c = half * 16 + 2 * i;
            const float a0 = fmaf(xf[2 * i],     sv[c],     tv[c]);
            const float a1 = fmaf(xf[2 * i + 1], sv[c + 1], tv[c + 1]);
            *(unsigned int*)(xs0 + px_ * 80 + (half * 16 + 2 * i) * 2) =
                ((unsigned int)bf16u(a1) << 16) | bf16u(a0);
        }
    }
    __syncthreads();
    #pragma unroll
    for (int ks = 0; ks < 8; ++ks) {
        char* xcur = (ks & 1) ? xs1 : xs0;
        char* xnxt = (ks & 1) ? xs0 : xs1;
        float xg[16];
        if (ks < 7) {                        // issue next-tile loads EARLY
            #pragma unroll
            for (int i = 0; i < 16; ++i)
                xg[i] = xb[(size_t)((ks + 1) * 32 + half * 16 + i) * N_ + px_];
        }
        #pragma unroll
        for (int ct = 0; ct < 8; ++ct) {     // MFMA on current buffer
            const short8b bfr = *(const short8b*)(xcur + (pxw + ct * 16 + (l & 15)) * 80
                                                  + (l >> 4) * 16);
            accq[ct] = __builtin_amdgcn_mfma_f32_16x16x32_bf16(
                           afq[ks], bfr, accq[ct], 0, 0, 0);
        }
        if (ks < 7) {                        // fold + write next buffer LATE
            #pragma unroll
            for (int i = 0; i < 8; ++i) {
                const int c = (ks + 1) * 32 + half * 16 + 2 * i;
                const float a0 = fmaf(xg[2 * i],     sv[c],     tv[c]);
                const float a1 = fmaf(xg[2 * i + 1], sv[c + 1], tv[c + 1]);
                *(unsigned int*)(xnxt + px_ * 80 + (half * 16 + 2 * i) * 2) =
                    ((unsigned int)bf16u(a1) << 16) | bf16u(a0);
            }
        }
        __syncthreads();
    }

    // ---- W2 = Wo·M^T -> w2_s (aliases x staging; phase 1 fully drained) ----
    char* w2_s = breg;                       // [256][128B] XOR-swizzled
    {
        const int c = t & 255, hp = t >> 8;  // 2 heads per thread
        #pragma unroll
        for (int hh = 0; hh < 2; ++hh) {
            const int hw = hp * 2 + hh;
            float wrow[16];
            #pragma unroll
            for (int j = 0; j < 4; ++j)
                *(float4*)&wrow[j * 4] = *(const float4*)&Wo[c * 64 + hw * 16 + j * 4];
            float av[16];
            #pragma unroll
            for (int d = 0; d < 16; ++d) {
                float a = 0.f;
                #pragma unroll
                for (int e = 0; e < 16; ++e)
                    a = fmaf(wrow[e], m_s[hw * 256 + d * 16 + e], a);
                av[d] = a;
            }
            #pragma unroll
            for (int j = 0; j < 8; ++j) {
                const unsigned int pk = (unsigned int)bf16u(av[2 * j])
                                      | ((unsigned int)bf16u(av[2 * j + 1]) << 16);
                *(unsigned int*)(w2_s + c * 128 + ((hw * 32 + j * 4) ^ ((c & 7) << 4))) = pk;
            }
        }
    }
    __syncthreads();   // m_s reads done before psi overwrites pq_s

    // ---- phi, per-pixel den (in-wave shuffle), psi -> pq_s (swizzled) ----
    #pragma unroll
    for (int ct = 0; ct < 8; ++ct) {
        float p[4];
        #pragma unroll
        for (int r = 0; r < 4; ++r) {
            const float v = accq[ct][r];
            p[r] = v > 0.f ? v + 1.f : __expf(v);
        }
        float dp = 0.f;
        #pragma unroll
        for (int r = 0; r < 4; ++r) dp = fmaf(zr[r], p[r], dp);
        dp += __shfl_xor(dp, 16);
        dp += __shfl_xor(dp, 32);
        const float rd = 1.f / fmaxf(dp, 1e-4f);
        const int px = pxw + ct * 16 + (l & 15);
        const unsigned int lo = (unsigned int)bf16u(p[0] * rd)
                              | ((unsigned int)bf16u(p[1] * rd) << 16);
        const unsigned int hi = (unsigned int)bf16u(p[2] * rd)
                              | ((unsigned int)bf16u(p[3] * rd) << 16);
        const int off = (h * 32 + (l >> 4) * 8) ^ ((px & 7) << 4);
        *(unsigned long long*)(pq_s + px * 128 + off) =
            (unsigned long long)lo | ((unsigned long long)hi << 32);
    }
    __syncthreads();   // psi + W2 visible to all waves

    // ---- phase 3: out = W2 · psi (K=64); B-frags streamed from LDS ----
    const float gate = ws[OFF_GATE + b];
    const float* __restrict__ xr = x + (size_t)b * C_ * N_ + px0;
    float* __restrict__ ob = out + (size_t)b * C_ * N_ + px0;
    #pragma unroll
    for (int rt = 0; rt < 4; ++rt) {
        f32x4 acc[8];
        #pragma unroll
        for (int j = 0; j < 8; ++j) acc[j] = (f32x4){0.f, 0.f, 0.f, 0.f};
        const int row = h * 64 + rt * 16 + (l & 15);
        #pragma unroll
        for (int ksi = 0; ksi < 2; ++ksi) {
            const short8b af = *(const short8b*)(w2_s + row * 128
                                 + ((ksi * 64 + (l >> 4) * 16) ^ ((row & 7) << 4)));
            #pragma unroll
            for (int ct = 0; ct < 8; ++ct) {
                const int px = pxw + ct * 16 + (l & 15);
                const short8b bfr = *(const short8b*)(pq_s + px * 128
                                 + ((ksi * 64 + (l >> 4) * 16) ^ ((px & 7) << 4)));
                acc[ct] = __builtin_amdgcn_mfma_f32_16x16x32_bf16(
                              af, bfr, acc[ct], 0, 0, 0);
            }
        }
        #pragma unroll
        for (int ct = 0; ct < 8; ++ct) {
            const int px = pxw + ct * 16 + (l & 15);
            #pragma unroll
            for (int r = 0; r < 4; ++r) {
                const int orow = h * 64 + rt * 16 + (l >> 4) * 4 + r;
                const size_t off = (size_t)orow * N_ + px;
                ob[off] = fmaf(gate, acc[ct][r] + bo_s[orow], xr[off]);
            }
        }
    }
}

// ---------------------------------------------------------------------------
extern "C" void kernel_launch(void* const* d_in, const int* in_sizes, int n_in,
                              void* d_out, int out_size, void* d_ws, size_t ws_size,
                              hipStream_t stream) {
    const float* x   = (const float*)d_in[0];
    const float* gnw = (const float*)d_in[1];
    const float* gnb = (const float*)d_in[2];
    const float* Wk  = (const float*)d_in[3];
    const float* Wv  = (const float*)d_in[4];
    const float* Wq  = (const float*)d_in[5];
    const float* Wo  = (const float*)d_in[6];
    const float* bo  = (const float*)d_in[7];
    const float* M0  = (const float*)d_in[8];
    const float* Z0  = (const float*)d_in[9];
    const float* g1w = (const float*)d_in[10];
    const float* g1b = (const float*)d_in[11];
    const float* g2w = (const float*)d_in[12];
    const float* g2b = (const float*)d_in[13];
    float* out = (float*)d_out;
    float* ws  = (float*)d_ws;

    hipLaunchKernelGGL(k_stats,  dim3(B_ * C_), dim3(256), 0, stream, x, ws);
    hipLaunchKernelGGL(k_cvtw,   dim3(192),     dim3(256), 0, stream, Wk, Wv, Wq, ws);
    hipLaunchKernelGGL(k_prep,   dim3(B_),      dim3(256), 0, stream,
                       gnw, gnb, M0, Z0, g1w, g1b, g2w, g2b, ws,
                       out + (size_t)B_ * C_ * N_);
    hipLaunchKernelGGL(k_projmz, dim3(N_ / 128, B_), dim3(256), 0, stream, x, ws);
    hipLaunchKernelGGL(k_out5,   dim3(N_ / 256, B_), dim3(512), 0, stream,
                       x, Wo, bo, ws, out);
}